// Round 17
// baseline (194.244 us; speedup 1.0000x reference)
//
#include <hip/hip_runtime.h>
#include <hip/hip_fp16.h>
#include <cstdint>

#define B_   16
#define H_   128
#define W_   128
#define C_   64
#define HID_ 256
#define XELEMS (B_ * H_ * W_ * C_)   // 16777216

typedef _Float16 __attribute__((ext_vector_type(2))) half2v;
typedef _Float16 __attribute__((ext_vector_type(8))) half8v;   // MFMA frag, 4 VGPRs
typedef __attribute__((ext_vector_type(4))) float f32x4;
typedef unsigned short ushort_t;

// ws layout (in _Float16 elements)
#define W1S_OFF 0
#define W2S_OFF 81920
#define CWH_OFF 98304
#define XH_OFF  100608
#define FEAT_OFF (XH_OFF + XELEMS)                  // 16877824
#define FEAT_HALVES (4096ull * 16384ull)            // [tile][ks8][px64][c32]
#define WS_NEED_FULL (2ull * (FEAT_OFF + FEAT_HALVES))   // ~168 MB

// Bijective XOR-swizzled LDS index, row stride 256 halves (512 B).
__device__ __forceinline__ int hs(int row, int col) {
  return row * 256 + (((col >> 3) ^ (row & 7)) << 3) + (col & 7);
}

// scalar fast tanh-GELU (fallback path)
__device__ __forceinline__ float fast_gelu(float h) {
  float u = h * fmaf(h * h, 0.10293921f, 2.30211813f);
  float e = exp2f(-u);
  return h * __builtin_amdgcn_rcpf(1.0f + e);
}

// packed-f16 GELU (proven: mlp VALUBusy 38.6 -> ~24).
__device__ __forceinline__ uint32_t fast_gelu_pk(float h0, float h1) {
  half2v h = __builtin_bit_cast(half2v, __builtin_amdgcn_cvt_pkrtz(h0, h1));
  const half2v c1 = {(_Float16)0.10293921f, (_Float16)0.10293921f};
  const half2v c0 = {(_Float16)2.30211813f, (_Float16)2.30211813f};
  half2v u = h * (c0 + h * h * c1);
  __half2 e = h2exp2(__hneg2(__builtin_bit_cast(__half2, u)));
  const __half2 one = __half2{(__half)1.0f, (__half)1.0f};
  __half2 s = h2rcp(__hadd2(one, e));
  __half2 g = __hmul2(__builtin_bit_cast(__half2, h), s);
  return __builtin_bit_cast(uint32_t, g);
}

// async global->LDS, 16B per lane: LDS dest = wave-uniform base + lane*16.
__device__ __forceinline__ void stage16(const _Float16* g, const ushort_t* l) {
  __builtin_amdgcn_global_load_lds(
      (const __attribute__((address_space(1))) void*)g,
      (__attribute__((address_space(3))) void*)l, 16, 0, 0);
}

__device__ __forceinline__ half2v bch(uint32_t u) {
  return __builtin_bit_cast(half2v, u);
}

// ---------------------------------------------------------------------------
// prep: blocks [0,393): W1/W2 -> fp16 MFMA fragments + conv_w -> fp16.
//       blocks [393,...): x fp32 -> fp16 copy.
// ---------------------------------------------------------------------------
__global__ void prep_kernel(const float* __restrict__ x,
                            const float* __restrict__ W1,
                            const float* __restrict__ W2,
                            const float* __restrict__ cw,
                            _Float16* __restrict__ wsb) {
  if (blockIdx.x < 393) {
    int t = blockIdx.x * 256 + threadIdx.x;
    if (t < 81920) {
      int j = t & 7, lane = (t >> 3) & 63, n16 = (t >> 9) & 15, ks = t >> 13;
      int k = ks * 32 + (lane >> 4) * 8 + j;
      int n = n16 * 16 + (lane & 15);
      wsb[W1S_OFF + t] = (_Float16)W1[k * 256 + n];
    } else if (t < 98304) {
      int t2 = t - 81920;
      int j = t2 & 7, lane = (t2 >> 3) & 63, n16 = (t2 >> 9) & 3, ks = t2 >> 11;
      int k = ks * 32 + (lane >> 4) * 8 + j;
      int n = n16 * 16 + (lane & 15);
      wsb[W2S_OFF + t2] = (_Float16)W2[k * 64 + n];
    } else if (t < 98304 + 2304) {
      int t3 = t - 98304;
      wsb[CWH_OFF + t3] = (_Float16)cw[t3];   // [(dd*9+ky*3+kx)*64 + ch]
    }
  } else {
    int i = ((blockIdx.x - 393) * 256 + threadIdx.x) * 8;
    const float4 a = *(const float4*)&x[i];
    const float4 b = *(const float4*)&x[i + 4];
    half8v o = {(_Float16)a.x, (_Float16)a.y, (_Float16)a.z, (_Float16)a.w,
                (_Float16)b.x, (_Float16)b.y, (_Float16)b.z, (_Float16)b.w};
    *(half8v*)&wsb[XH_OFF + i] = o;
  }
}

// ---------------------------------------------------------------------------
// Boundary (register, predicated) conv path — rare tiles, runtime dil.
// ---------------------------------------------------------------------------
__device__ void conv_boundary(const _Float16* __restrict__ xhb,
                              const _Float16* __restrict__ cwh,
                              _Float16* __restrict__ ft,
                              int tid, int tileX, int tileY, int dil, int dd) {
  const int quad = tid & 15;
  const int p0   = tid >> 4;
  const int ksq  = quad >> 3;
  const int c32  = (quad & 7) * 4;

  half2v w01[9], w23[9];
#pragma unroll
  for (int t = 0; t < 9; ++t) {
    uint2 wr = *(const uint2*)&cwh[(dd * 9 + t) * C_ + quad * 4];
    w01[t] = bch(wr.x);
    w23[t] = bch(wr.y);
  }
#pragma unroll
  for (int i = 0; i < 4; ++i) {
    const int p  = i * 16 + p0;
    const int y0 = tileY + (p >> 3), x0 = tileX + (p & 7);
    half2v a01 = {0, 0}, a23 = {0, 0};
#pragma unroll
    for (int ky = 0; ky < 3; ++ky) {
      const int yy = y0 + (ky - 1) * dil;
#pragma unroll
      for (int kx = 0; kx < 3; ++kx) {
        const int xx = x0 + (kx - 1) * dil;
        uint2 vv = {0u, 0u};
        if ((unsigned)yy < (unsigned)H_ && (unsigned)xx < (unsigned)W_)
          vv = *(const uint2*)&xhb[(yy * W_ + xx) * C_ + quad * 4];
        const int t = ky * 3 + kx;
        a01 += bch(vv.x) * w01[t];
        a23 += bch(vv.y) * w23[t];
      }
    }
    uint2 pk;
    pk.x = __builtin_bit_cast(uint32_t, a01);
    pk.y = __builtin_bit_cast(uint32_t, a23);
    *(uint2*)&ft[(dd * 2 + ksq) * 2048 + p * 32 + c32] = pk;
  }
}

// ---------------------------------------------------------------------------
// conv_all (round-13 version, proven): grid z = batch*4 + dd.
//  dd<3 interior: stage (8+2*dil)x16-px region to LDS, taps via ds_read_b64.
//  dd==3: register path, 18x uint4 loads + asm liveness pin.
// ---------------------------------------------------------------------------
__global__ __launch_bounds__(256, 2)
void conv_all_kernel(const _Float16* __restrict__ xh,
                     const _Float16* __restrict__ cwh,
                     _Float16* __restrict__ feat) {
  __shared__ __align__(16) ushort_t lds[16 * 1024];   // 32 KB (R<=16 rows)

  const int tid   = threadIdx.x;
  const int tileX = blockIdx.x * 8;
  const int tileY = blockIdx.y * 8;
  const int batch = blockIdx.z >> 2;
  const int dd    = blockIdx.z & 3;
  const int dil   = 1 << dd;

  const _Float16* xhb = xh + (size_t)batch * (H_ * W_ * C_);
  _Float16* ft =
      feat + ((size_t)((batch * 16 + blockIdx.y) * 16 + blockIdx.x)) * 16384;

  const bool interior = (tileX >= 8) && (tileX <= W_ - 16) &&
                        (tileY >= 8) && (tileY <= H_ - 16);

  if (dd == 3) {
    const int c8 = tid & 7;
    const int p0 = tid >> 3;
    const int ksq = c8 >> 2;
    const int cof = (c8 & 3) * 8;

    uint4 wv4[9];
#pragma unroll
    for (int t = 0; t < 9; ++t)
      wv4[t] = *(const uint4*)&cwh[(3 * 9 + t) * C_ + c8 * 8];

    uint4 v[2][9];
#pragma unroll
    for (int i = 0; i < 2; ++i) {
      const int p  = i * 32 + p0;
      const int y0 = tileY + (p >> 3), x0 = tileX + (p & 7);
      if (interior) {
#pragma unroll
        for (int ky = 0; ky < 3; ++ky)
#pragma unroll
          for (int kx = 0; kx < 3; ++kx)
            v[i][ky * 3 + kx] = *(const uint4*)
                &xhb[((y0 + (ky - 1) * 8) * W_ + x0 + (kx - 1) * 8) * C_ +
                     c8 * 8];
      } else {
#pragma unroll
        for (int ky = 0; ky < 3; ++ky)
#pragma unroll
          for (int kx = 0; kx < 3; ++kx) {
            const int yy = y0 + (ky - 1) * 8;
            const int xx = x0 + (kx - 1) * 8;
            uint4 vv = {0u, 0u, 0u, 0u};
            if ((unsigned)yy < (unsigned)H_ && (unsigned)xx < (unsigned)W_)
              vv = *(const uint4*)&xhb[(yy * W_ + xx) * C_ + c8 * 8];
            v[i][ky * 3 + kx] = vv;
          }
      }
    }
#pragma unroll
    for (int i = 0; i < 2; ++i)
#pragma unroll
      for (int t = 0; t < 9; ++t)
        asm volatile("" : "+v"(v[i][t].x), "+v"(v[i][t].y),
                          "+v"(v[i][t].z), "+v"(v[i][t].w));

#pragma unroll
    for (int i = 0; i < 2; ++i) {
      const int p = i * 32 + p0;
      half2v a0 = {0, 0}, a1 = {0, 0}, a2 = {0, 0}, a3 = {0, 0};
#pragma unroll
      for (int t = 0; t < 9; ++t) {
        a0 += bch(v[i][t].x) * bch(wv4[t].x);
        a1 += bch(v[i][t].y) * bch(wv4[t].y);
        a2 += bch(v[i][t].z) * bch(wv4[t].z);
        a3 += bch(v[i][t].w) * bch(wv4[t].w);
      }
      uint4 pk;
      pk.x = __builtin_bit_cast(uint32_t, a0);
      pk.y = __builtin_bit_cast(uint32_t, a1);
      pk.z = __builtin_bit_cast(uint32_t, a2);
      pk.w = __builtin_bit_cast(uint32_t, a3);
      *(uint4*)&ft[(3 * 2 + ksq) * 2048 + p * 32 + cof] = pk;
    }
    return;
  }

  if (!interior) {
    conv_boundary(xhb, cwh, ft, tid, tileX, tileY, dil, dd);
    return;
  }

  const int lane = tid & 63;
  const int wv   = tid >> 6;
  const int quad = tid & 15;
  const int p0   = tid >> 4;
  const int ksq  = quad >> 3;
  const int c32  = (quad & 7) * 4;
  const int R    = 8 + 2 * dil;

  {
    const int x0 = tileX - dil, y0 = tileY - dil;
    for (int s = wv; s < 2 * R; s += 4) {
      const int row = s >> 1, half = s & 1;
      const _Float16* g =
          &xhb[((y0 + row) * W_ + x0 + half * 8 + (lane >> 3)) * C_ +
               (lane & 7) * 8];
      stage16(g, &lds[row * 1024 + half * 512]);
    }
  }

  half2v w01[9], w23[9];
#pragma unroll
  for (int t = 0; t < 9; ++t) {
    uint2 wr = *(const uint2*)&cwh[(dd * 9 + t) * C_ + quad * 4];
    w01[t] = bch(wr.x);
    w23[t] = bch(wr.y);
  }

  __syncthreads();   // drains vmcnt(0): region resident

#pragma unroll
  for (int i = 0; i < 4; ++i) {
    const int p  = i * 16 + p0;
    const int py = p >> 3, px = p & 7;
    uint2 tv[9];
#pragma unroll
    for (int ky = 0; ky < 3; ++ky)
#pragma unroll
      for (int kx = 0; kx < 3; ++kx)
        tv[ky * 3 + kx] = *(const uint2*)
            &lds[(py + ky * dil) * 1024 + (px + kx * dil) * 64 + quad * 4];
    half2v a01 = {0, 0}, a23 = {0, 0};
#pragma unroll
    for (int t = 0; t < 9; ++t) {
      a01 += bch(tv[t].x) * w01[t];
      a23 += bch(tv[t].y) * w23[t];
    }
    uint2 pk;
    pk.x = __builtin_bit_cast(uint32_t, a01);
    pk.y = __builtin_bit_cast(uint32_t, a23);
    *(uint2*)&ft[(dd * 2 + ksq) * 2048 + p * 32 + c32] = pk;
  }
}

// ---------------------------------------------------------------------------
// mlp v8: EXACT round-13 structure (proven 91us, launch_bounds(256,4)).
// GEMM2 swapped (r16-verified free: same VGPR/occupancy) -> D[out][px];
// epilogue VECTORIZED with fp16-xh residual (r13-verified precision):
// 4x uint2 xh loads (8B) + 4x float4 stores, vs r13's 16+16 scalars and
// r16's fp32-x reads (the diagnosed +17MB FETCH regression).
// ---------------------------------------------------------------------------
__global__ __launch_bounds__(256, 4)
void mlp_kernel(const _Float16* __restrict__ xh,
                const _Float16* __restrict__ feat,
                const float* __restrict__ b1,
                const float* __restrict__ b2,
                const _Float16* __restrict__ w1s,
                const _Float16* __restrict__ w2s,
                float* __restrict__ out) {
  __shared__ __align__(16) ushort_t smem[64 * 256];   // 32 KB

  const int tid   = threadIdx.x;
  const int tileX = blockIdx.x * 8;
  const int tileY = blockIdx.y * 8;
  const int batch = blockIdx.z;
  const _Float16* xhb = xh + (size_t)batch * (H_ * W_ * C_);
  const _Float16* ftb =
      feat + ((size_t)((batch * 16 + blockIdx.y) * 16 + blockIdx.x)) * 16384;

  const int lane = tid & 63;
  const int wv   = tid >> 6;
  const int lr   = lane & 15;
  const int lg   = lane >> 4;
  const int n0   = wv * 64;

  const half8v* w1v = (const half8v*)w1s;

  // ---- x-channel fragments (K=0..63) issued first ----
  half8v xf[4][2];
#pragma unroll
  for (int pi = 0; pi < 4; ++pi) {
    const int p  = pi * 16 + lr;
    const int gp = (tileY + (p >> 3)) * W_ + tileX + (p & 7);
#pragma unroll
    for (int ks = 0; ks < 2; ++ks)
      xf[pi][ks] = *(const half8v*)&xhb[gp * C_ + ks * 32 + lg * 8];
  }

  // ---- async-stage feat: wave wv stages pi=wv, 8 ks steps ----
  {
    const _Float16* src0 = &ftb[(wv * 16 + lr) * 32 + lg * 8];
#pragma unroll
    for (int s = 0; s < 8; ++s)
      stage16(src0 + s * 2048, &smem[(s * 4 + wv) * 512]);
  }

  f32x4 acc[4][4];   // [hi][pi]
#pragma unroll
  for (int hi = 0; hi < 4; ++hi)
#pragma unroll
    for (int pi = 0; pi < 4; ++pi) acc[hi][pi] = 0;

  // ---- ks=0,1 from x registers while stages are in flight ----
#pragma unroll
  for (int ks = 0; ks < 2; ++ks) {
    half8v wf[4];
#pragma unroll
    for (int hi = 0; hi < 4; ++hi)
      wf[hi] = w1v[(ks * 16 + wv * 4 + hi) * 64 + lane];
#pragma unroll
    for (int hi = 0; hi < 4; ++hi)
#pragma unroll
      for (int pi = 0; pi < 4; ++pi)
        acc[hi][pi] = __builtin_amdgcn_mfma_f32_16x16x32_f16(
            wf[hi], xf[pi][ks], acc[hi][pi], 0, 0, 0);
  }

  // bias1 prefetched: latency hidden under the main loop
  float4 bias1[4];
#pragma unroll
  for (int hi = 0; hi < 4; ++hi)
    bias1[hi] = *(const float4*)&b1[n0 + hi * 16 + lg * 4];

  __syncthreads();   // drains vmcnt(0): staged feat resident

  // ---- main loop ks=2..9 (round-13 proven form) ----
#define LOAD_W(WB, S)                                                         \
  _Pragma("unroll") for (int hi = 0; hi < 4; ++hi)                            \
      WB[hi] = w1v[((S) * 16 + wv * 4 + hi) * 64 + lane];
#define LOAD_F(FB, S)                                                         \
  _Pragma("unroll") for (int pi = 0; pi < 4; ++pi)                            \
      FB[pi] = *(const half8v*)&smem[(((S) - 2) * 4 + pi) * 512 + lane * 8];
#define MFMA16(WB, FB)                                                        \
  _Pragma("unroll") for (int hi = 0; hi < 4; ++hi)                            \
      _Pragma("unroll") for (int pi = 0; pi < 4; ++pi)                        \
      acc[hi][pi] = __builtin_amdgcn_mfma_f32_16x16x32_f16(                   \
          WB[hi], FB[pi], acc[hi][pi], 0, 0, 0);

  {
    half8v wfA[4], wfB[4], fA[4];
    LOAD_W(wfA, 2);
    LOAD_F(fA, 2); LOAD_W(wfB, 3); MFMA16(wfA, fA);
    LOAD_F(fA, 3); LOAD_W(wfA, 4); MFMA16(wfB, fA);
    LOAD_F(fA, 4); LOAD_W(wfB, 5); MFMA16(wfA, fA);
    LOAD_F(fA, 5); LOAD_W(wfA, 6); MFMA16(wfB, fA);
    LOAD_F(fA, 6); LOAD_W(wfB, 7); MFMA16(wfA, fA);
    LOAD_F(fA, 7); LOAD_W(wfA, 8); MFMA16(wfB, fA);
    LOAD_F(fA, 8); LOAD_W(wfB, 9); MFMA16(wfA, fA);
    LOAD_F(fA, 9);                 MFMA16(wfB, fA);
  }

  __syncthreads();   // staged-feat reads done; safe to alias with hbuf

  // ---- bias + packed-f16 GELU -> hbuf[px][hid] (8B writes) ----
#pragma unroll
  for (int hi = 0; hi < 4; ++hi) {
#pragma unroll
    for (int pi = 0; pi < 4; ++pi) {
      uint2 pk;
      pk.x = fast_gelu_pk(acc[hi][pi][0] + bias1[hi][0],
                          acc[hi][pi][1] + bias1[hi][1]);
      pk.y = fast_gelu_pk(acc[hi][pi][2] + bias1[hi][2],
                          acc[hi][pi][3] + bias1[hi][3]);
      *(uint2*)&smem[hs(pi * 16 + lr, n0 + hi * 16 + lg * 4)] = pk;
    }
  }
  __syncthreads();

  // ---- GEMM2 SWAPPED (r16-verified): D[out 64][px 16] per wave ----
  const int m0 = wv * 16;
  f32x4 acc2[4];   // [oi]: out channels oi*16+lg*4+q, pixel m0+lr
#pragma unroll
  for (int oi = 0; oi < 4; ++oi) acc2[oi] = 0;

  const half8v* w2v = (const half8v*)w2s;
#pragma unroll 2
  for (int ks = 0; ks < 8; ++ks) {
    half8v a2 = *(const half8v*)&smem[hs(m0 + lr, ks * 32 + lg * 8)];
#pragma unroll
    for (int oi = 0; oi < 4; ++oi) {
      half8v bfr = w2v[(ks * 4 + oi) * 64 + lane];
      acc2[oi] = __builtin_amdgcn_mfma_f32_16x16x32_f16(bfr, a2, acc2[oi],
                                                        0, 0, 0);
    }
  }

  // ---- epilogue: out = xh + delta + b2; fp16 residual (8B loads),
  //      float4 stores. ----
  {
    const int p  = m0 + lr;                 // this thread's pixel
    const int py = p >> 3, px = p & 7;
    const size_t base =
        ((size_t)(batch * H_ + tileY + py) * W_ + (tileX + px)) * C_;
#pragma unroll
    for (int oi = 0; oi < 4; ++oi) {
      const int ch = oi * 16 + lg * 4;
      const uint2 xr = *(const uint2*)&xh[base + ch];   // 4 fp16
      const half2v x01 = bch(xr.x), x23 = bch(xr.y);
      const float4 bb = *(const float4*)&b2[ch];
      float4 o;
      o.x = (float)x01[0] + acc2[oi][0] + bb.x;
      o.y = (float)x01[1] + acc2[oi][1] + bb.y;
      o.z = (float)x23[0] + acc2[oi][2] + bb.z;
      o.w = (float)x23[1] + acc2[oi][3] + bb.w;
      *(float4*)&out[base + ch] = o;
    }
  }
#undef LOAD_W
#undef LOAD_F
#undef MFMA16
}

// ---------------------------------------------------------------------------
// FALLBACK (ws too small): fused fp32-x kernel (round-5 structure).
// ---------------------------------------------------------------------------
template <bool BOUND>
__device__ __forceinline__ void conv_phase_f32(const float* __restrict__ xb,
                                               const _Float16* __restrict__ cwh,
                                               ushort_t* __restrict__ feat,
                                               int tid, int tileX, int tileY) {
  const int quad = tid & 15;
  const int p0   = tid >> 4;
#pragma unroll
  for (int dd = 0; dd < 4; ++dd) {
    const int dil = 1 << dd;
    half2v w01[9], w23[9];
#pragma unroll
    for (int t = 0; t < 9; ++t) {
      uint2 wr = *(const uint2*)&cwh[(dd * 9 + t) * C_ + quad * 4];
      w01[t] = bch(wr.x);
      w23[t] = bch(wr.y);
    }
#pragma unroll
    for (int i = 0; i < 4; ++i) {
      const int p  = i * 16 + p0;
      const int y0 = tileY + (p >> 3), x0 = tileX + (p & 7);
      half2v a01 = {0, 0}, a23 = {0, 0};
#pragma unroll
      for (int ky = 0; ky < 3; ++ky) {
        const int yy = y0 + (ky - 1) * dil;
        if (BOUND && (unsigned)yy >= (unsigned)H_) continue;
#pragma unroll
        for (int kx = 0; kx < 3; ++kx) {
          const int xx = x0 + (kx - 1) * dil;
          if (BOUND && (unsigned)xx >= (unsigned)W_) continue;
          const int t = ky * 3 + kx;
          const float4 xv = *(const float4*)&xb[(yy * W_ + xx) * C_ + quad * 4];
          half2v xl = {(_Float16)xv.x, (_Float16)xv.y};
          half2v xh2 = {(_Float16)xv.z, (_Float16)xv.w};
          a01 += xl * w01[t];
          a23 += xh2 * w23[t];
        }
      }
      uint2 pk;
      pk.x = __builtin_bit_cast(uint32_t, a01);
      pk.y = __builtin_bit_cast(uint32_t, a23);
      *(uint2*)&feat[hs(p, dd * 64 + quad * 4)] = pk;
    }
  }
}

__global__ __launch_bounds__(256, 4)
void nca_fused_fp32(const float* __restrict__ x,
                    const _Float16* __restrict__ cwh,
                    const float* __restrict__ b1,
                    const float* __restrict__ b2,
                    const _Float16* __restrict__ w1s,
                    const _Float16* __restrict__ w2s,
                    float* __restrict__ out) {
  __shared__ __align__(16) ushort_t smem[64 * 256];

  const int tid   = threadIdx.x;
  const int tileX = blockIdx.x * 8;
  const int tileY = blockIdx.y * 8;
  const int batch = blockIdx.z;
  const float* xb = x + (size_t)batch * (H_ * W_ * C_);

  const int lane = tid & 63;
  const int wv   = tid >> 6;
  const int lr   = lane & 15;
  const int lg   = lane >> 4;
  const int n0   = wv * 64;

  half8v xf[4][2];
#pragma unroll
  for (int pi = 0; pi < 4; ++pi) {
    const int p  = pi * 16 + lr;
    const int gp = (tileY + (p >> 3)) * W_ + tileX + (p & 7);
#pragma unroll
    for (int ks = 0; ks < 2; ++ks) {
      const float* bp = &xb[gp * C_ + ks * 32 + lg * 8];
      float4 u = *(const float4*)bp, v = *(const float4*)(bp + 4);
      half8v s = {(_Float16)u.x, (_Float16)u.y, (_Float16)u.z, (_Float16)u.w,
                  (_Float16)v.x, (_Float16)v.y, (_Float16)v.z, (_Float16)v.w};
      xf[pi][ks] = s;
    }
  }

  const bool interior = (tileX >= 8) && (tileX <= W_ - 16) &&
                        (tileY >= 8) && (tileY <= H_ - 16);
  if (interior)
    conv_phase_f32<false>(xb, cwh, smem, tid, tileX, tileY);
  else
    conv_phase_f32<true>(xb, cwh, smem, tid, tileX, tileY);
  __syncthreads();

  f32x4 acc[4][4];
#pragma unroll
  for (int hi = 0; hi < 4; ++hi)
#pragma unroll
    for (int pi = 0; pi < 4; ++pi) acc[hi][pi] = 0;

  const half8v* w1v = (const half8v*)w1s;
#pragma unroll
  for (int ks = 0; ks < 2; ++ks) {
    half8v wf[4];
#pragma unroll
    for (int hi = 0; hi < 4; ++hi)
      wf[hi] = w1v[(ks * 16 + wv * 4 + hi) * 64 + lane];
#pragma unroll
    for (int hi = 0; hi < 4; ++hi)
#pragma unroll
      for (int pi = 0; pi < 4; ++pi)
        acc[hi][pi] = __builtin_amdgcn_mfma_f32_16x16x32_f16(
            wf[hi], xf[pi][ks], acc[hi][pi], 0, 0, 0);
  }
  for (int ks = 2; ks < 10; ++ks) {
    half8v ff[4], wf[4];
#pragma unroll
    for (int pi = 0; pi < 4; ++pi)
      ff[pi] = *(const half8v*)&smem[hs(pi * 16 + lr, (ks - 2) * 32 + lg * 8)];
#pragma unroll
    for (int hi = 0; hi < 4; ++hi)
      wf[hi] = w1v[(ks * 16 + wv * 4 + hi) * 64 + lane];
#pragma unroll
    for (int hi = 0; hi < 4; ++hi)
#pragma unroll
      for (int pi = 0; pi < 4; ++pi)
        acc[hi][pi] = __builtin_amdgcn_mfma_f32_16x16x32_f16(
            wf[hi], ff[pi], acc[hi][pi], 0, 0, 0);
  }

  float4 bias1[4];
#pragma unroll
  for (int hi = 0; hi < 4; ++hi)
    bias1[hi] = *(const float4*)&b1[n0 + hi * 16 + lg * 4];

  __syncthreads();

#pragma unroll
  for (int hi = 0; hi < 4; ++hi) {
#pragma unroll
    for (int pi = 0; pi < 4; ++pi) {
      _Float16 g[4];
#pragma unroll
      for (int q = 0; q < 4; ++q)
        g[q] = (_Float16)fast_gelu(acc[hi][pi][q] + bias1[hi][q]);
      half2v g01 = {g[0], g[1]}, g23 = {g[2], g[3]};
      uint2 pk;
      pk.x = __builtin_bit_cast(uint32_t, g01);
      pk.y = __builtin_bit_cast(uint32_t, g23);
      *(uint2*)&smem[hs(pi * 16 + lr, n0 + hi * 16 + lg * 4)] = pk;
    }
  }
  __syncthreads();

  const int m0 = wv * 16;
  f32x4 acc2[4];
#pragma unroll
  for (int ni = 0; ni < 4; ++ni) acc2[ni] = 0;

  const half8v* w2v = (const half8v*)w2s;
  for (int ks = 0; ks < 8; ++ks) {
    half8v a2 = *(const half8v*)&smem[hs(m0 + lr, ks * 32 + lg * 8)];
#pragma unroll
    for (int ni = 0; ni < 4; ++ni) {
      half8v bfr = w2v[(ks * 4 + ni) * 64 + lane];
      acc2[ni] = __builtin_amdgcn_mfma_f32_16x16x32_f16(a2, bfr, acc2[ni],
                                                        0, 0, 0);
    }
  }

#pragma unroll
  for (int ni = 0; ni < 4; ++ni) {
    const int col  = ni * 16 + lr;
    const float bias = b2[col];
#pragma unroll
    for (int q = 0; q < 4; ++q) {
      const int row = m0 + lg * 4 + q;
      const int py = row >> 3, px = row & 7;
      const size_t idx =
          ((size_t)(batch * H_ + tileY + py) * W_ + (tileX + px)) * C_ + col;
      out[idx] = x[idx] + acc2[ni][q] + bias;
    }
  }
}

extern "C" void kernel_launch(void* const* d_in, const int* in_sizes, int n_in,
                              void* d_out, int out_size, void* d_ws,
                              size_t ws_size, hipStream_t stream) {
  const float* x  = (const float*)d_in[0];
  const float* cw = (const float*)d_in[1];
  const float* W1 = (const float*)d_in[2];
  const float* b1 = (const float*)d_in[3];
  const float* W2 = (const float*)d_in[4];
  const float* b2 = (const float*)d_in[5];
  float* out = (float*)d_out;

  _Float16* wsb  = (_Float16*)d_ws;
  _Float16* w1s  = wsb + W1S_OFF;
  _Float16* w2s  = wsb + W2S_OFF;
  _Float16* cwh  = wsb + CWH_OFF;
  _Float16* xh   = wsb + XH_OFF;
  _Float16* feat = wsb + FEAT_OFF;

  if (ws_size >= (size_t)WS_NEED_FULL) {
    prep_kernel<<<393 + XELEMS / 8 / 256, 256, 0, stream>>>(x, W1, W2, cw, wsb);
    dim3 cgrid(W_ / 8, H_ / 8, B_ * 4);       // one dilation per block
    conv_all_kernel<<<cgrid, 256, 0, stream>>>(xh, cwh, feat);
    dim3 mgrid(W_ / 8, H_ / 8, B_);
    mlp_kernel<<<mgrid, 256, 0, stream>>>(xh, feat, b1, b2, w1s, w2s, out);
  } else {
    prep_kernel<<<393, 256, 0, stream>>>(x, W1, W2, cw, wsb);   // weights only
    dim3 grid(W_ / 8, H_ / 8, B_);
    nca_fused_fp32<<<grid, 256, 0, stream>>>(x, cwh, b1, b2, w1s, w2s, out);
  }
}

// Round 18
// 182.212 us; speedup vs baseline: 1.0660x; 1.0660x over previous
//
#include <hip/hip_runtime.h>
#include <hip/hip_fp16.h>
#include <cstdint>

#define B_   16
#define H_   128
#define W_   128
#define C_   64
#define HID_ 256
#define XELEMS (B_ * H_ * W_ * C_)   // 16777216

typedef _Float16 __attribute__((ext_vector_type(2))) half2v;
typedef _Float16 __attribute__((ext_vector_type(8))) half8v;   // MFMA frag, 4 VGPRs
typedef __attribute__((ext_vector_type(4))) float f32x4;
typedef unsigned short ushort_t;

// ws layout (in _Float16 elements)
#define W1S_OFF 0
#define W2S_OFF 81920
#define CWH_OFF 98304
#define XH_OFF  100608
#define FEAT_OFF (XH_OFF + XELEMS)                  // 16877824
#define FEAT_HALVES (4096ull * 16384ull)            // [tile][ks8][px64][c32]
#define WS_NEED_FULL (2ull * (FEAT_OFF + FEAT_HALVES))   // ~168 MB

// Bijective XOR-swizzled LDS index, row stride 256 halves (512 B).
__device__ __forceinline__ int hs(int row, int col) {
  return row * 256 + (((col >> 3) ^ (row & 7)) << 3) + (col & 7);
}

// scalar fast tanh-GELU (fallback path)
__device__ __forceinline__ float fast_gelu(float h) {
  float u = h * fmaf(h * h, 0.10293921f, 2.30211813f);
  float e = exp2f(-u);
  return h * __builtin_amdgcn_rcpf(1.0f + e);
}

// packed-f16 GELU (proven: mlp VALUBusy 38.6 -> ~24).
__device__ __forceinline__ uint32_t fast_gelu_pk(float h0, float h1) {
  half2v h = __builtin_bit_cast(half2v, __builtin_amdgcn_cvt_pkrtz(h0, h1));
  const half2v c1 = {(_Float16)0.10293921f, (_Float16)0.10293921f};
  const half2v c0 = {(_Float16)2.30211813f, (_Float16)2.30211813f};
  half2v u = h * (c0 + h * h * c1);
  __half2 e = h2exp2(__hneg2(__builtin_bit_cast(__half2, u)));
  const __half2 one = __half2{(__half)1.0f, (__half)1.0f};
  __half2 s = h2rcp(__hadd2(one, e));
  __half2 g = __hmul2(__builtin_bit_cast(__half2, h), s);
  return __builtin_bit_cast(uint32_t, g);
}

// async global->LDS, 16B per lane: LDS dest = wave-uniform base + lane*16.
__device__ __forceinline__ void stage16(const _Float16* g, const ushort_t* l) {
  __builtin_amdgcn_global_load_lds(
      (const __attribute__((address_space(1))) void*)g,
      (__attribute__((address_space(3))) void*)l, 16, 0, 0);
}

__device__ __forceinline__ half2v bch(uint32_t u) {
  return __builtin_bit_cast(half2v, u);
}

// ---------------------------------------------------------------------------
// prep: blocks [0,393): W1/W2 -> fp16 MFMA fragments + conv_w -> fp16.
//       blocks [393,...): x fp32 -> fp16 copy.
// ---------------------------------------------------------------------------
__global__ void prep_kernel(const float* __restrict__ x,
                            const float* __restrict__ W1,
                            const float* __restrict__ W2,
                            const float* __restrict__ cw,
                            _Float16* __restrict__ wsb) {
  if (blockIdx.x < 393) {
    int t = blockIdx.x * 256 + threadIdx.x;
    if (t < 81920) {
      int j = t & 7, lane = (t >> 3) & 63, n16 = (t >> 9) & 15, ks = t >> 13;
      int k = ks * 32 + (lane >> 4) * 8 + j;
      int n = n16 * 16 + (lane & 15);
      wsb[W1S_OFF + t] = (_Float16)W1[k * 256 + n];
    } else if (t < 98304) {
      int t2 = t - 81920;
      int j = t2 & 7, lane = (t2 >> 3) & 63, n16 = (t2 >> 9) & 3, ks = t2 >> 11;
      int k = ks * 32 + (lane >> 4) * 8 + j;
      int n = n16 * 16 + (lane & 15);
      wsb[W2S_OFF + t2] = (_Float16)W2[k * 64 + n];
    } else if (t < 98304 + 2304) {
      int t3 = t - 98304;
      wsb[CWH_OFF + t3] = (_Float16)cw[t3];   // [(dd*9+ky*3+kx)*64 + ch]
    }
  } else {
    int i = ((blockIdx.x - 393) * 256 + threadIdx.x) * 8;
    const float4 a = *(const float4*)&x[i];
    const float4 b = *(const float4*)&x[i + 4];
    half8v o = {(_Float16)a.x, (_Float16)a.y, (_Float16)a.z, (_Float16)a.w,
                (_Float16)b.x, (_Float16)b.y, (_Float16)b.z, (_Float16)b.w};
    *(half8v*)&wsb[XH_OFF + i] = o;
  }
}

// ---------------------------------------------------------------------------
// Boundary (register, predicated) conv path — rare tiles, runtime dil.
// ---------------------------------------------------------------------------
__device__ void conv_boundary(const _Float16* __restrict__ xhb,
                              const _Float16* __restrict__ cwh,
                              _Float16* __restrict__ ft,
                              int tid, int tileX, int tileY, int dil, int dd) {
  const int quad = tid & 15;
  const int p0   = tid >> 4;
  const int ksq  = quad >> 3;
  const int c32  = (quad & 7) * 4;

  half2v w01[9], w23[9];
#pragma unroll
  for (int t = 0; t < 9; ++t) {
    uint2 wr = *(const uint2*)&cwh[(dd * 9 + t) * C_ + quad * 4];
    w01[t] = bch(wr.x);
    w23[t] = bch(wr.y);
  }
#pragma unroll
  for (int i = 0; i < 4; ++i) {
    const int p  = i * 16 + p0;
    const int y0 = tileY + (p >> 3), x0 = tileX + (p & 7);
    half2v a01 = {0, 0}, a23 = {0, 0};
#pragma unroll
    for (int ky = 0; ky < 3; ++ky) {
      const int yy = y0 + (ky - 1) * dil;
#pragma unroll
      for (int kx = 0; kx < 3; ++kx) {
        const int xx = x0 + (kx - 1) * dil;
        uint2 vv = {0u, 0u};
        if ((unsigned)yy < (unsigned)H_ && (unsigned)xx < (unsigned)W_)
          vv = *(const uint2*)&xhb[(yy * W_ + xx) * C_ + quad * 4];
        const int t = ky * 3 + kx;
        a01 += bch(vv.x) * w01[t];
        a23 += bch(vv.y) * w23[t];
      }
    }
    uint2 pk;
    pk.x = __builtin_bit_cast(uint32_t, a01);
    pk.y = __builtin_bit_cast(uint32_t, a23);
    *(uint2*)&ft[(dd * 2 + ksq) * 2048 + p * 32 + c32] = pk;
  }
}

// ---------------------------------------------------------------------------
// conv_all (round-13 version, proven): grid z = batch*4 + dd.
//  dd<3 interior: stage (8+2*dil)x16-px region to LDS, taps via ds_read_b64.
//  dd==3: register path, 18x uint4 loads + asm liveness pin.
// ---------------------------------------------------------------------------
__global__ __launch_bounds__(256, 2)
void conv_all_kernel(const _Float16* __restrict__ xh,
                     const _Float16* __restrict__ cwh,
                     _Float16* __restrict__ feat) {
  __shared__ __align__(16) ushort_t lds[16 * 1024];   // 32 KB (R<=16 rows)

  const int tid   = threadIdx.x;
  const int tileX = blockIdx.x * 8;
  const int tileY = blockIdx.y * 8;
  const int batch = blockIdx.z >> 2;
  const int dd    = blockIdx.z & 3;
  const int dil   = 1 << dd;

  const _Float16* xhb = xh + (size_t)batch * (H_ * W_ * C_);
  _Float16* ft =
      feat + ((size_t)((batch * 16 + blockIdx.y) * 16 + blockIdx.x)) * 16384;

  const bool interior = (tileX >= 8) && (tileX <= W_ - 16) &&
                        (tileY >= 8) && (tileY <= H_ - 16);

  if (dd == 3) {
    const int c8 = tid & 7;
    const int p0 = tid >> 3;
    const int ksq = c8 >> 2;
    const int cof = (c8 & 3) * 8;

    uint4 wv4[9];
#pragma unroll
    for (int t = 0; t < 9; ++t)
      wv4[t] = *(const uint4*)&cwh[(3 * 9 + t) * C_ + c8 * 8];

    uint4 v[2][9];
#pragma unroll
    for (int i = 0; i < 2; ++i) {
      const int p  = i * 32 + p0;
      const int y0 = tileY + (p >> 3), x0 = tileX + (p & 7);
      if (interior) {
#pragma unroll
        for (int ky = 0; ky < 3; ++ky)
#pragma unroll
          for (int kx = 0; kx < 3; ++kx)
            v[i][ky * 3 + kx] = *(const uint4*)
                &xhb[((y0 + (ky - 1) * 8) * W_ + x0 + (kx - 1) * 8) * C_ +
                     c8 * 8];
      } else {
#pragma unroll
        for (int ky = 0; ky < 3; ++ky)
#pragma unroll
          for (int kx = 0; kx < 3; ++kx) {
            const int yy = y0 + (ky - 1) * 8;
            const int xx = x0 + (kx - 1) * 8;
            uint4 vv = {0u, 0u, 0u, 0u};
            if ((unsigned)yy < (unsigned)H_ && (unsigned)xx < (unsigned)W_)
              vv = *(const uint4*)&xhb[(yy * W_ + xx) * C_ + c8 * 8];
            v[i][ky * 3 + kx] = vv;
          }
      }
    }
#pragma unroll
    for (int i = 0; i < 2; ++i)
#pragma unroll
      for (int t = 0; t < 9; ++t)
        asm volatile("" : "+v"(v[i][t].x), "+v"(v[i][t].y),
                          "+v"(v[i][t].z), "+v"(v[i][t].w));

#pragma unroll
    for (int i = 0; i < 2; ++i) {
      const int p = i * 32 + p0;
      half2v a0 = {0, 0}, a1 = {0, 0}, a2 = {0, 0}, a3 = {0, 0};
#pragma unroll
      for (int t = 0; t < 9; ++t) {
        a0 += bch(v[i][t].x) * bch(wv4[t].x);
        a1 += bch(v[i][t].y) * bch(wv4[t].y);
        a2 += bch(v[i][t].z) * bch(wv4[t].z);
        a3 += bch(v[i][t].w) * bch(wv4[t].w);
      }
      uint4 pk;
      pk.x = __builtin_bit_cast(uint32_t, a0);
      pk.y = __builtin_bit_cast(uint32_t, a1);
      pk.z = __builtin_bit_cast(uint32_t, a2);
      pk.w = __builtin_bit_cast(uint32_t, a3);
      *(uint4*)&ft[(3 * 2 + ksq) * 2048 + p * 32 + cof] = pk;
    }
    return;
  }

  if (!interior) {
    conv_boundary(xhb, cwh, ft, tid, tileX, tileY, dil, dd);
    return;
  }

  const int lane = tid & 63;
  const int wv   = tid >> 6;
  const int quad = tid & 15;
  const int p0   = tid >> 4;
  const int ksq  = quad >> 3;
  const int c32  = (quad & 7) * 4;
  const int R    = 8 + 2 * dil;

  {
    const int x0 = tileX - dil, y0 = tileY - dil;
    for (int s = wv; s < 2 * R; s += 4) {
      const int row = s >> 1, half = s & 1;
      const _Float16* g =
          &xhb[((y0 + row) * W_ + x0 + half * 8 + (lane >> 3)) * C_ +
               (lane & 7) * 8];
      stage16(g, &lds[row * 1024 + half * 512]);
    }
  }

  half2v w01[9], w23[9];
#pragma unroll
  for (int t = 0; t < 9; ++t) {
    uint2 wr = *(const uint2*)&cwh[(dd * 9 + t) * C_ + quad * 4];
    w01[t] = bch(wr.x);
    w23[t] = bch(wr.y);
  }

  __syncthreads();   // drains vmcnt(0): region resident

#pragma unroll
  for (int i = 0; i < 4; ++i) {
    const int p  = i * 16 + p0;
    const int py = p >> 3, px = p & 7;
    uint2 tv[9];
#pragma unroll
    for (int ky = 0; ky < 3; ++ky)
#pragma unroll
      for (int kx = 0; kx < 3; ++kx)
        tv[ky * 3 + kx] = *(const uint2*)
            &lds[(py + ky * dil) * 1024 + (px + kx * dil) * 64 + quad * 4];
    half2v a01 = {0, 0}, a23 = {0, 0};
#pragma unroll
    for (int t = 0; t < 9; ++t) {
      a01 += bch(tv[t].x) * w01[t];
      a23 += bch(tv[t].y) * w23[t];
    }
    uint2 pk;
    pk.x = __builtin_bit_cast(uint32_t, a01);
    pk.y = __builtin_bit_cast(uint32_t, a23);
    *(uint2*)&ft[(dd * 2 + ksq) * 2048 + p * 32 + c32] = pk;
  }
}

// ---------------------------------------------------------------------------
// mlp (EXACT round-13 version — empirical best, 91us / 181.2us total):
// feat async-staged to LDS via global_load_lds; xf register path covers
// stage latency; wf double-buffer; packed-f16 GELU -> hbuf alias; GEMM2
// unswapped; column-major scalar epilogue (64B-contiguous stores per
// instruction -> no partial-sector RFO; r16/r17's pixel-major float4
// epilogue cost +17MB FETCH / +13us).
// ---------------------------------------------------------------------------
__global__ __launch_bounds__(256, 4)
void mlp_kernel(const _Float16* __restrict__ xh,
                const _Float16* __restrict__ feat,
                const float* __restrict__ b1,
                const float* __restrict__ b2,
                const _Float16* __restrict__ w1s,
                const _Float16* __restrict__ w2s,
                float* __restrict__ out) {
  __shared__ __align__(16) ushort_t smem[64 * 256];   // 32 KB

  const int tid   = threadIdx.x;
  const int tileX = blockIdx.x * 8;
  const int tileY = blockIdx.y * 8;
  const int batch = blockIdx.z;
  const _Float16* xhb = xh + (size_t)batch * (H_ * W_ * C_);
  const _Float16* ftb =
      feat + ((size_t)((batch * 16 + blockIdx.y) * 16 + blockIdx.x)) * 16384;

  const int lane = tid & 63;
  const int wv   = tid >> 6;
  const int lr   = lane & 15;
  const int lg   = lane >> 4;
  const int n0   = wv * 64;

  const half8v* w1v = (const half8v*)w1s;

  // ---- x-channel fragments (K=0..63) issued first ----
  half8v xf[4][2];
#pragma unroll
  for (int pi = 0; pi < 4; ++pi) {
    const int p  = pi * 16 + lr;
    const int gp = (tileY + (p >> 3)) * W_ + tileX + (p & 7);
#pragma unroll
    for (int ks = 0; ks < 2; ++ks)
      xf[pi][ks] = *(const half8v*)&xhb[gp * C_ + ks * 32 + lg * 8];
  }

  // ---- async-stage feat: wave wv stages pi=wv, 8 ks steps ----
  {
    const _Float16* src0 = &ftb[(wv * 16 + lr) * 32 + lg * 8];
#pragma unroll
    for (int s = 0; s < 8; ++s)
      stage16(src0 + s * 2048, &smem[(s * 4 + wv) * 512]);
  }

  f32x4 acc[4][4];   // [hi][pi]
#pragma unroll
  for (int hi = 0; hi < 4; ++hi)
#pragma unroll
    for (int pi = 0; pi < 4; ++pi) acc[hi][pi] = 0;

  // ---- ks=0,1 from x registers while stages are in flight ----
#pragma unroll
  for (int ks = 0; ks < 2; ++ks) {
    half8v wf[4];
#pragma unroll
    for (int hi = 0; hi < 4; ++hi)
      wf[hi] = w1v[(ks * 16 + wv * 4 + hi) * 64 + lane];
#pragma unroll
    for (int hi = 0; hi < 4; ++hi)
#pragma unroll
      for (int pi = 0; pi < 4; ++pi)
        acc[hi][pi] = __builtin_amdgcn_mfma_f32_16x16x32_f16(
            wf[hi], xf[pi][ks], acc[hi][pi], 0, 0, 0);
  }

  __syncthreads();   // drains vmcnt(0): staged feat resident

  // ---- main loop ks=2..9: ff from LDS, wf double-buffered from global ----
#define LOAD_W(WB, S)                                                         \
  _Pragma("unroll") for (int hi = 0; hi < 4; ++hi)                            \
      WB[hi] = w1v[((S) * 16 + wv * 4 + hi) * 64 + lane];
#define LOAD_F(FB, S)                                                         \
  _Pragma("unroll") for (int pi = 0; pi < 4; ++pi)                            \
      FB[pi] = *(const half8v*)&smem[(((S) - 2) * 4 + pi) * 512 + lane * 8];
#define MFMA16(WB, FB)                                                        \
  _Pragma("unroll") for (int hi = 0; hi < 4; ++hi)                            \
      _Pragma("unroll") for (int pi = 0; pi < 4; ++pi)                        \
      acc[hi][pi] = __builtin_amdgcn_mfma_f32_16x16x32_f16(                   \
          WB[hi], FB[pi], acc[hi][pi], 0, 0, 0);

  {
    half8v wfA[4], wfB[4], fA[4];
    LOAD_W(wfA, 2);
    LOAD_F(fA, 2); LOAD_W(wfB, 3); MFMA16(wfA, fA);
    LOAD_F(fA, 3); LOAD_W(wfA, 4); MFMA16(wfB, fA);
    LOAD_F(fA, 4); LOAD_W(wfB, 5); MFMA16(wfA, fA);
    LOAD_F(fA, 5); LOAD_W(wfA, 6); MFMA16(wfB, fA);
    LOAD_F(fA, 6); LOAD_W(wfB, 7); MFMA16(wfA, fA);
    LOAD_F(fA, 7); LOAD_W(wfA, 8); MFMA16(wfB, fA);
    LOAD_F(fA, 8); LOAD_W(wfB, 9); MFMA16(wfA, fA);
    LOAD_F(fA, 9);                 MFMA16(wfB, fA);
  }

  float4 bias1[4];
#pragma unroll
  for (int hi = 0; hi < 4; ++hi)
    bias1[hi] = *(const float4*)&b1[n0 + hi * 16 + lg * 4];

  __syncthreads();   // staged-feat reads done; safe to alias with hbuf

  // ---- bias + packed-f16 GELU -> hbuf[px][hid] (8B writes) ----
#pragma unroll
  for (int hi = 0; hi < 4; ++hi) {
#pragma unroll
    for (int pi = 0; pi < 4; ++pi) {
      uint2 pk;
      pk.x = fast_gelu_pk(acc[hi][pi][0] + bias1[hi][0],
                          acc[hi][pi][1] + bias1[hi][1]);
      pk.y = fast_gelu_pk(acc[hi][pi][2] + bias1[hi][2],
                          acc[hi][pi][3] + bias1[hi][3]);
      *(uint2*)&smem[hs(pi * 16 + lr, n0 + hi * 16 + lg * 4)] = pk;
    }
  }
  __syncthreads();

  // ---- GEMM2: D[px 64][out 64]; wave wv does pixel rows 16wv..16wv+15 ----
  const int m0 = wv * 16;
  f32x4 acc2[4];
#pragma unroll
  for (int ni = 0; ni < 4; ++ni) acc2[ni] = 0;

  const half8v* w2v = (const half8v*)w2s;
#pragma unroll 2
  for (int ks = 0; ks < 8; ++ks) {
    half8v a2 = *(const half8v*)&smem[hs(m0 + lr, ks * 32 + lg * 8)];
#pragma unroll
    for (int ni = 0; ni < 4; ++ni) {
      half8v bfr = w2v[(ks * 4 + ni) * 64 + lane];
      acc2[ni] = __builtin_amdgcn_mfma_f32_16x16x32_f16(a2, bfr, acc2[ni],
                                                        0, 0, 0);
    }
  }

  // ---- epilogue: out = x + delta + b2 (x from fp16 copy; column-major,
  //      64B-contiguous stores per instruction) ----
#pragma unroll
  for (int ni = 0; ni < 4; ++ni) {
    const int col  = ni * 16 + lr;
    const float bias = b2[col];
#pragma unroll
    for (int q = 0; q < 4; ++q) {
      const int row = m0 + lg * 4 + q;
      const int py = row >> 3, px = row & 7;
      const size_t idx =
          ((size_t)(batch * H_ + tileY + py) * W_ + (tileX + px)) * C_ + col;
      out[idx] = (float)xh[idx] + acc2[ni][q] + bias;
    }
  }
#undef LOAD_W
#undef LOAD_F
#undef MFMA16
}

// ---------------------------------------------------------------------------
// FALLBACK (ws too small): fused fp32-x kernel (round-5 structure).
// ---------------------------------------------------------------------------
template <bool BOUND>
__device__ __forceinline__ void conv_phase_f32(const float* __restrict__ xb,
                                               const _Float16* __restrict__ cwh,
                                               ushort_t* __restrict__ feat,
                                               int tid, int tileX, int tileY) {
  const int quad = tid & 15;
  const int p0   = tid >> 4;
#pragma unroll
  for (int dd = 0; dd < 4; ++dd) {
    const int dil = 1 << dd;
    half2v w01[9], w23[9];
#pragma unroll
    for (int t = 0; t < 9; ++t) {
      uint2 wr = *(const uint2*)&cwh[(dd * 9 + t) * C_ + quad * 4];
      w01[t] = bch(wr.x);
      w23[t] = bch(wr.y);
    }
#pragma unroll
    for (int i = 0; i < 4; ++i) {
      const int p  = i * 16 + p0;
      const int y0 = tileY + (p >> 3), x0 = tileX + (p & 7);
      half2v a01 = {0, 0}, a23 = {0, 0};
#pragma unroll
      for (int ky = 0; ky < 3; ++ky) {
        const int yy = y0 + (ky - 1) * dil;
        if (BOUND && (unsigned)yy >= (unsigned)H_) continue;
#pragma unroll
        for (int kx = 0; kx < 3; ++kx) {
          const int xx = x0 + (kx - 1) * dil;
          if (BOUND && (unsigned)xx >= (unsigned)W_) continue;
          const int t = ky * 3 + kx;
          const float4 xv = *(const float4*)&xb[(yy * W_ + xx) * C_ + quad * 4];
          half2v xl = {(_Float16)xv.x, (_Float16)xv.y};
          half2v xh2 = {(_Float16)xv.z, (_Float16)xv.w};
          a01 += xl * w01[t];
          a23 += xh2 * w23[t];
        }
      }
      uint2 pk;
      pk.x = __builtin_bit_cast(uint32_t, a01);
      pk.y = __builtin_bit_cast(uint32_t, a23);
      *(uint2*)&feat[hs(p, dd * 64 + quad * 4)] = pk;
    }
  }
}

__global__ __launch_bounds__(256, 4)
void nca_fused_fp32(const float* __restrict__ x,
                    const _Float16* __restrict__ cwh,
                    const float* __restrict__ b1,
                    const float* __restrict__ b2,
                    const _Float16* __restrict__ w1s,
                    const _Float16* __restrict__ w2s,
                    float* __restrict__ out) {
  __shared__ __align__(16) ushort_t smem[64 * 256];

  const int tid   = threadIdx.x;
  const int tileX = blockIdx.x * 8;
  const int tileY = blockIdx.y * 8;
  const int batch = blockIdx.z;
  const float* xb = x + (size_t)batch * (H_ * W_ * C_);

  const int lane = tid & 63;
  const int wv   = tid >> 6;
  const int lr   = lane & 15;
  const int lg   = lane >> 4;
  const int n0   = wv * 64;

  half8v xf[4][2];
#pragma unroll
  for (int pi = 0; pi < 4; ++pi) {
    const int p  = pi * 16 + lr;
    const int gp = (tileY + (p >> 3)) * W_ + tileX + (p & 7);
#pragma unroll
    for (int ks = 0; ks < 2; ++ks) {
      const float* bp = &xb[gp * C_ + ks * 32 + lg * 8];
      float4 u = *(const float4*)bp, v = *(const float4*)(bp + 4);
      half8v s = {(_Float16)u.x, (_Float16)u.y, (_Float16)u.z, (_Float16)u.w,
                  (_Float16)v.x, (_Float16)v.y, (_Float16)v.z, (_Float16)v.w};
      xf[pi][ks] = s;
    }
  }

  const bool interior = (tileX >= 8) && (tileX <= W_ - 16) &&
                        (tileY >= 8) && (tileY <= H_ - 16);
  if (interior)
    conv_phase_f32<false>(xb, cwh, smem, tid, tileX, tileY);
  else
    conv_phase_f32<true>(xb, cwh, smem, tid, tileX, tileY);
  __syncthreads();

  f32x4 acc[4][4];
#pragma unroll
  for (int hi = 0; hi < 4; ++hi)
#pragma unroll
    for (int pi = 0; pi < 4; ++pi) acc[hi][pi] = 0;

  const half8v* w1v = (const half8v*)w1s;
#pragma unroll
  for (int ks = 0; ks < 2; ++ks) {
    half8v wf[4];
#pragma unroll
    for (int hi = 0; hi < 4; ++hi)
      wf[hi] = w1v[(ks * 16 + wv * 4 + hi) * 64 + lane];
#pragma unroll
    for (int hi = 0; hi < 4; ++hi)
#pragma unroll
      for (int pi = 0; pi < 4; ++pi)
        acc[hi][pi] = __builtin_amdgcn_mfma_f32_16x16x32_f16(
            wf[hi], xf[pi][ks], acc[hi][pi], 0, 0, 0);
  }
  for (int ks = 2; ks < 10; ++ks) {
    half8v ff[4], wf[4];
#pragma unroll
    for (int pi = 0; pi < 4; ++pi)
      ff[pi] = *(const half8v*)&smem[hs(pi * 16 + lr, (ks - 2) * 32 + lg * 8)];
#pragma unroll
    for (int hi = 0; hi < 4; ++hi)
      wf[hi] = w1v[(ks * 16 + wv * 4 + hi) * 64 + lane];
#pragma unroll
    for (int hi = 0; hi < 4; ++hi)
#pragma unroll
      for (int pi = 0; pi < 4; ++pi)
        acc[hi][pi] = __builtin_amdgcn_mfma_f32_16x16x32_f16(
            wf[hi], ff[pi], acc[hi][pi], 0, 0, 0);
  }

  float4 bias1[4];
#pragma unroll
  for (int hi = 0; hi < 4; ++hi)
    bias1[hi] = *(const float4*)&b1[n0 + hi * 16 + lg * 4];

  __syncthreads();

#pragma unroll
  for (int hi = 0; hi < 4; ++hi) {
#pragma unroll
    for (int pi = 0; pi < 4; ++pi) {
      _Float16 g[4];
#pragma unroll
      for (int q = 0; q < 4; ++q)
        g[q] = (_Float16)fast_gelu(acc[hi][pi][q] + bias1[hi][q]);
      half2v g01 = {g[0], g[1]}, g23 = {g[2], g[3]};
      uint2 pk;
      pk.x = __builtin_bit_cast(uint32_t, g01);
      pk.y = __builtin_bit_cast(uint32_t, g23);
      *(uint2*)&smem[hs(pi * 16 + lr, n0 + hi * 16 + lg * 4)] = pk;
    }
  }
  __syncthreads();

  const int m0 = wv * 16;
  f32x4 acc2[4];
#pragma unroll
  for (int ni = 0; ni < 4; ++ni) acc2[ni] = 0;

  const half8v* w2v = (const half8v*)w2s;
  for (int ks = 0; ks < 8; ++ks) {
    half8v a2 = *(const half8v*)&smem[hs(m0 + lr, ks * 32 + lg * 8)];
#pragma unroll
    for (int ni = 0; ni < 4; ++ni) {
      half8v bfr = w2v[(ks * 4 + ni) * 64 + lane];
      acc2[ni] = __builtin_amdgcn_mfma_f32_16x16x32_f16(a2, bfr, acc2[ni],
                                                        0, 0, 0);
    }
  }

#pragma unroll
  for (int ni = 0; ni < 4; ++ni) {
    const int col  = ni * 16 + lr;
    const float bias = b2[col];
#pragma unroll
    for (int q = 0; q < 4; ++q) {
      const int row = m0 + lg * 4 + q;
      const int py = row >> 3, px = row & 7;
      const size_t idx =
          ((size_t)(batch * H_ + tileY + py) * W_ + (tileX + px)) * C_ + col;
      out[idx] = x[idx] + acc2[ni][q] + bias;
    }
  }
}

extern "C" void kernel_launch(void* const* d_in, const int* in_sizes, int n_in,
                              void* d_out, int out_size, void* d_ws,
                              size_t ws_size, hipStream_t stream) {
  const float* x  = (const float*)d_in[0];
  const float* cw = (const float*)d_in[1];
  const float* W1 = (const float*)d_in[2];
  const float* b1 = (const float*)d_in[3];
  const float* W2 = (const float*)d_in[4];
  const float* b2 = (const float*)d_in[5];
  float* out = (float*)d_out;

  _Float16* wsb  = (_Float16*)d_ws;
  _Float16* w1s  = wsb + W1S_OFF;
  _Float16* w2s  = wsb + W2S_OFF;
  _Float16* cwh  = wsb + CWH_OFF;
  _Float16* xh   = wsb + XH_OFF;
  _Float16* feat = wsb + FEAT_OFF;

  if (ws_size >= (size_t)WS_NEED_FULL) {
    prep_kernel<<<393 + XELEMS / 8 / 256, 256, 0, stream>>>(x, W1, W2, cw, wsb);
    dim3 cgrid(W_ / 8, H_ / 8, B_ * 4);       // one dilation per block
    conv_all_kernel<<<cgrid, 256, 0, stream>>>(xh, cwh, feat);
    dim3 mgrid(W_ / 8, H_ / 8, B_);
    mlp_kernel<<<mgrid, 256, 0, stream>>>(xh, feat, b1, b2, w1s, w2s, out);
  } else {
    prep_kernel<<<393, 256, 0, stream>>>(x, W1, W2, cw, wsb);   // weights only
    dim3 grid(W_ / 8, H_ / 8, B_);
    nca_fused_fp32<<<grid, 256, 0, stream>>>(x, cwh, b1, b2, w1s, w2s, out);
  }
}

// Round 19
// 181.393 us; speedup vs baseline: 1.0708x; 1.0045x over previous
//
#include <hip/hip_runtime.h>
#include <hip/hip_fp16.h>
#include <cstdint>

#define B_   16
#define H_   128
#define W_   128
#define C_   64
#define HID_ 256
#define XELEMS (B_ * H_ * W_ * C_)   // 16777216

typedef _Float16 __attribute__((ext_vector_type(2))) half2v;
typedef _Float16 __attribute__((ext_vector_type(8))) half8v;   // MFMA frag, 4 VGPRs
typedef __attribute__((ext_vector_type(4))) float f32x4;
typedef unsigned short ushort_t;

// ws layout (in _Float16 elements)
#define W1S_OFF 0
#define W2S_OFF 81920
#define CWH_OFF 98304
#define XH_OFF  100608
#define FEAT_OFF (XH_OFF + XELEMS)                  // 16877824
#define FEAT_HALVES (4096ull * 16384ull)            // [tile][ks8][px64][c32]
#define WS_NEED_FULL (2ull * (FEAT_OFF + FEAT_HALVES))   // ~168 MB

// Bijective XOR-swizzled LDS index, row stride 256 halves (512 B).
__device__ __forceinline__ int hs(int row, int col) {
  return row * 256 + (((col >> 3) ^ (row & 7)) << 3) + (col & 7);
}

// scalar fast tanh-GELU (fallback path)
__device__ __forceinline__ float fast_gelu(float h) {
  float u = h * fmaf(h * h, 0.10293921f, 2.30211813f);
  float e = exp2f(-u);
  return h * __builtin_amdgcn_rcpf(1.0f + e);
}

// packed-f16 GELU (proven: mlp VALUBusy 38.6 -> ~24).
__device__ __forceinline__ uint32_t fast_gelu_pk(float h0, float h1) {
  half2v h = __builtin_bit_cast(half2v, __builtin_amdgcn_cvt_pkrtz(h0, h1));
  const half2v c1 = {(_Float16)0.10293921f, (_Float16)0.10293921f};
  const half2v c0 = {(_Float16)2.30211813f, (_Float16)2.30211813f};
  half2v u = h * (c0 + h * h * c1);
  __half2 e = h2exp2(__hneg2(__builtin_bit_cast(__half2, u)));
  const __half2 one = __half2{(__half)1.0f, (__half)1.0f};
  __half2 s = h2rcp(__hadd2(one, e));
  __half2 g = __hmul2(__builtin_bit_cast(__half2, h), s);
  return __builtin_bit_cast(uint32_t, g);
}

// async global->LDS, 16B per lane: LDS dest = wave-uniform base + lane*16.
__device__ __forceinline__ void stage16(const _Float16* g, const ushort_t* l) {
  __builtin_amdgcn_global_load_lds(
      (const __attribute__((address_space(1))) void*)g,
      (__attribute__((address_space(3))) void*)l, 16, 0, 0);
}

__device__ __forceinline__ half2v bch(uint32_t u) {
  return __builtin_bit_cast(half2v, u);
}

// ---------------------------------------------------------------------------
// prep: blocks [0,393): W1/W2 -> fp16 MFMA fragments + conv_w -> fp16.
//       blocks [393,...): x fp32 -> fp16 copy.
// ---------------------------------------------------------------------------
__global__ void prep_kernel(const float* __restrict__ x,
                            const float* __restrict__ W1,
                            const float* __restrict__ W2,
                            const float* __restrict__ cw,
                            _Float16* __restrict__ wsb) {
  if (blockIdx.x < 393) {
    int t = blockIdx.x * 256 + threadIdx.x;
    if (t < 81920) {
      int j = t & 7, lane = (t >> 3) & 63, n16 = (t >> 9) & 15, ks = t >> 13;
      int k = ks * 32 + (lane >> 4) * 8 + j;
      int n = n16 * 16 + (lane & 15);
      wsb[W1S_OFF + t] = (_Float16)W1[k * 256 + n];
    } else if (t < 98304) {
      int t2 = t - 81920;
      int j = t2 & 7, lane = (t2 >> 3) & 63, n16 = (t2 >> 9) & 3, ks = t2 >> 11;
      int k = ks * 32 + (lane >> 4) * 8 + j;
      int n = n16 * 16 + (lane & 15);
      wsb[W2S_OFF + t2] = (_Float16)W2[k * 64 + n];
    } else if (t < 98304 + 2304) {
      int t3 = t - 98304;
      wsb[CWH_OFF + t3] = (_Float16)cw[t3];   // [(dd*9+ky*3+kx)*64 + ch]
    }
  } else {
    int i = ((blockIdx.x - 393) * 256 + threadIdx.x) * 8;
    const float4 a = *(const float4*)&x[i];
    const float4 b = *(const float4*)&x[i + 4];
    half8v o = {(_Float16)a.x, (_Float16)a.y, (_Float16)a.z, (_Float16)a.w,
                (_Float16)b.x, (_Float16)b.y, (_Float16)b.z, (_Float16)b.w};
    *(half8v*)&wsb[XH_OFF + i] = o;
  }
}

// ---------------------------------------------------------------------------
// Boundary (register, predicated) conv path — rare tiles, runtime dil.
// ---------------------------------------------------------------------------
__device__ void conv_boundary(const _Float16* __restrict__ xhb,
                              const _Float16* __restrict__ cwh,
                              _Float16* __restrict__ ft,
                              int tid, int tileX, int tileY, int dil, int dd) {
  const int quad = tid & 15;
  const int p0   = tid >> 4;
  const int ksq  = quad >> 3;
  const int c32  = (quad & 7) * 4;

  half2v w01[9], w23[9];
#pragma unroll
  for (int t = 0; t < 9; ++t) {
    uint2 wr = *(const uint2*)&cwh[(dd * 9 + t) * C_ + quad * 4];
    w01[t] = bch(wr.x);
    w23[t] = bch(wr.y);
  }
#pragma unroll
  for (int i = 0; i < 4; ++i) {
    const int p  = i * 16 + p0;
    const int y0 = tileY + (p >> 3), x0 = tileX + (p & 7);
    half2v a01 = {0, 0}, a23 = {0, 0};
#pragma unroll
    for (int ky = 0; ky < 3; ++ky) {
      const int yy = y0 + (ky - 1) * dil;
#pragma unroll
      for (int kx = 0; kx < 3; ++kx) {
        const int xx = x0 + (kx - 1) * dil;
        uint2 vv = {0u, 0u};
        if ((unsigned)yy < (unsigned)H_ && (unsigned)xx < (unsigned)W_)
          vv = *(const uint2*)&xhb[(yy * W_ + xx) * C_ + quad * 4];
        const int t = ky * 3 + kx;
        a01 += bch(vv.x) * w01[t];
        a23 += bch(vv.y) * w23[t];
      }
    }
    uint2 pk;
    pk.x = __builtin_bit_cast(uint32_t, a01);
    pk.y = __builtin_bit_cast(uint32_t, a23);
    *(uint2*)&ft[(dd * 2 + ksq) * 2048 + p * 32 + c32] = pk;
  }
}

// ---------------------------------------------------------------------------
// conv_all: grid z = batch*4 + dd. ROUND-19 CHANGE: launch_bounds (256,2) ->
// (256,4). Budget check: d8 branch ~110 VGPR (72 pinned v + 18 w + addr)
// < 128; LDS 32KB allows 5 blocks/CU. 2->4 blocks/CU halves the grid's
// serial occupancy-rounds (16384 blocks / (256CU*k)).
//  dd<3 interior: stage (8+2*dil)x16-px region to LDS, taps via ds_read_b64.
//  dd==3: register path, 18x uint4 loads + asm liveness pin.
// ---------------------------------------------------------------------------
__global__ __launch_bounds__(256, 4)
void conv_all_kernel(const _Float16* __restrict__ xh,
                     const _Float16* __restrict__ cwh,
                     _Float16* __restrict__ feat) {
  __shared__ __align__(16) ushort_t lds[16 * 1024];   // 32 KB (R<=16 rows)

  const int tid   = threadIdx.x;
  const int tileX = blockIdx.x * 8;
  const int tileY = blockIdx.y * 8;
  const int batch = blockIdx.z >> 2;
  const int dd    = blockIdx.z & 3;
  const int dil   = 1 << dd;

  const _Float16* xhb = xh + (size_t)batch * (H_ * W_ * C_);
  _Float16* ft =
      feat + ((size_t)((batch * 16 + blockIdx.y) * 16 + blockIdx.x)) * 16384;

  const bool interior = (tileX >= 8) && (tileX <= W_ - 16) &&
                        (tileY >= 8) && (tileY <= H_ - 16);

  if (dd == 3) {
    const int c8 = tid & 7;
    const int p0 = tid >> 3;
    const int ksq = c8 >> 2;
    const int cof = (c8 & 3) * 8;

    uint4 wv4[9];
#pragma unroll
    for (int t = 0; t < 9; ++t)
      wv4[t] = *(const uint4*)&cwh[(3 * 9 + t) * C_ + c8 * 8];

    uint4 v[2][9];
#pragma unroll
    for (int i = 0; i < 2; ++i) {
      const int p  = i * 32 + p0;
      const int y0 = tileY + (p >> 3), x0 = tileX + (p & 7);
      if (interior) {
#pragma unroll
        for (int ky = 0; ky < 3; ++ky)
#pragma unroll
          for (int kx = 0; kx < 3; ++kx)
            v[i][ky * 3 + kx] = *(const uint4*)
                &xhb[((y0 + (ky - 1) * 8) * W_ + x0 + (kx - 1) * 8) * C_ +
                     c8 * 8];
      } else {
#pragma unroll
        for (int ky = 0; ky < 3; ++ky)
#pragma unroll
          for (int kx = 0; kx < 3; ++kx) {
            const int yy = y0 + (ky - 1) * 8;
            const int xx = x0 + (kx - 1) * 8;
            uint4 vv = {0u, 0u, 0u, 0u};
            if ((unsigned)yy < (unsigned)H_ && (unsigned)xx < (unsigned)W_)
              vv = *(const uint4*)&xhb[(yy * W_ + xx) * C_ + c8 * 8];
            v[i][ky * 3 + kx] = vv;
          }
      }
    }
#pragma unroll
    for (int i = 0; i < 2; ++i)
#pragma unroll
      for (int t = 0; t < 9; ++t)
        asm volatile("" : "+v"(v[i][t].x), "+v"(v[i][t].y),
                          "+v"(v[i][t].z), "+v"(v[i][t].w));

#pragma unroll
    for (int i = 0; i < 2; ++i) {
      const int p = i * 32 + p0;
      half2v a0 = {0, 0}, a1 = {0, 0}, a2 = {0, 0}, a3 = {0, 0};
#pragma unroll
      for (int t = 0; t < 9; ++t) {
        a0 += bch(v[i][t].x) * bch(wv4[t].x);
        a1 += bch(v[i][t].y) * bch(wv4[t].y);
        a2 += bch(v[i][t].z) * bch(wv4[t].z);
        a3 += bch(v[i][t].w) * bch(wv4[t].w);
      }
      uint4 pk;
      pk.x = __builtin_bit_cast(uint32_t, a0);
      pk.y = __builtin_bit_cast(uint32_t, a1);
      pk.z = __builtin_bit_cast(uint32_t, a2);
      pk.w = __builtin_bit_cast(uint32_t, a3);
      *(uint4*)&ft[(3 * 2 + ksq) * 2048 + p * 32 + cof] = pk;
    }
    return;
  }

  if (!interior) {
    conv_boundary(xhb, cwh, ft, tid, tileX, tileY, dil, dd);
    return;
  }

  const int lane = tid & 63;
  const int wv   = tid >> 6;
  const int quad = tid & 15;
  const int p0   = tid >> 4;
  const int ksq  = quad >> 3;
  const int c32  = (quad & 7) * 4;
  const int R    = 8 + 2 * dil;

  {
    const int x0 = tileX - dil, y0 = tileY - dil;
    for (int s = wv; s < 2 * R; s += 4) {
      const int row = s >> 1, half = s & 1;
      const _Float16* g =
          &xhb[((y0 + row) * W_ + x0 + half * 8 + (lane >> 3)) * C_ +
               (lane & 7) * 8];
      stage16(g, &lds[row * 1024 + half * 512]);
    }
  }

  half2v w01[9], w23[9];
#pragma unroll
  for (int t = 0; t < 9; ++t) {
    uint2 wr = *(const uint2*)&cwh[(dd * 9 + t) * C_ + quad * 4];
    w01[t] = bch(wr.x);
    w23[t] = bch(wr.y);
  }

  __syncthreads();   // drains vmcnt(0): region resident

#pragma unroll
  for (int i = 0; i < 4; ++i) {
    const int p  = i * 16 + p0;
    const int py = p >> 3, px = p & 7;
    uint2 tv[9];
#pragma unroll
    for (int ky = 0; ky < 3; ++ky)
#pragma unroll
      for (int kx = 0; kx < 3; ++kx)
        tv[ky * 3 + kx] = *(const uint2*)
            &lds[(py + ky * dil) * 1024 + (px + kx * dil) * 64 + quad * 4];
    half2v a01 = {0, 0}, a23 = {0, 0};
#pragma unroll
    for (int t = 0; t < 9; ++t) {
      a01 += bch(tv[t].x) * w01[t];
      a23 += bch(tv[t].y) * w23[t];
    }
    uint2 pk;
    pk.x = __builtin_bit_cast(uint32_t, a01);
    pk.y = __builtin_bit_cast(uint32_t, a23);
    *(uint2*)&ft[(dd * 2 + ksq) * 2048 + p * 32 + c32] = pk;
  }
}

// ---------------------------------------------------------------------------
// mlp (EXACT round-13 version — empirical best, 91us): feat async-staged to
// LDS via global_load_lds; xf register path covers stage latency; wf
// double-buffer; packed-f16 GELU -> hbuf alias; GEMM2 unswapped;
// column-major scalar epilogue (64B-contiguous stores -> no RFO penalty).
// ---------------------------------------------------------------------------
__global__ __launch_bounds__(256, 4)
void mlp_kernel(const _Float16* __restrict__ xh,
                const _Float16* __restrict__ feat,
                const float* __restrict__ b1,
                const float* __restrict__ b2,
                const _Float16* __restrict__ w1s,
                const _Float16* __restrict__ w2s,
                float* __restrict__ out) {
  __shared__ __align__(16) ushort_t smem[64 * 256];   // 32 KB

  const int tid   = threadIdx.x;
  const int tileX = blockIdx.x * 8;
  const int tileY = blockIdx.y * 8;
  const int batch = blockIdx.z;
  const _Float16* xhb = xh + (size_t)batch * (H_ * W_ * C_);
  const _Float16* ftb =
      feat + ((size_t)((batch * 16 + blockIdx.y) * 16 + blockIdx.x)) * 16384;

  const int lane = tid & 63;
  const int wv   = tid >> 6;
  const int lr   = lane & 15;
  const int lg   = lane >> 4;
  const int n0   = wv * 64;

  const half8v* w1v = (const half8v*)w1s;

  // ---- x-channel fragments (K=0..63) issued first ----
  half8v xf[4][2];
#pragma unroll
  for (int pi = 0; pi < 4; ++pi) {
    const int p  = pi * 16 + lr;
    const int gp = (tileY + (p >> 3)) * W_ + tileX + (p & 7);
#pragma unroll
    for (int ks = 0; ks < 2; ++ks)
      xf[pi][ks] = *(const half8v*)&xhb[gp * C_ + ks * 32 + lg * 8];
  }

  // ---- async-stage feat: wave wv stages pi=wv, 8 ks steps ----
  {
    const _Float16* src0 = &ftb[(wv * 16 + lr) * 32 + lg * 8];
#pragma unroll
    for (int s = 0; s < 8; ++s)
      stage16(src0 + s * 2048, &smem[(s * 4 + wv) * 512]);
  }

  f32x4 acc[4][4];   // [hi][pi]
#pragma unroll
  for (int hi = 0; hi < 4; ++hi)
#pragma unroll
    for (int pi = 0; pi < 4; ++pi) acc[hi][pi] = 0;

  // ---- ks=0,1 from x registers while stages are in flight ----
#pragma unroll
  for (int ks = 0; ks < 2; ++ks) {
    half8v wf[4];
#pragma unroll
    for (int hi = 0; hi < 4; ++hi)
      wf[hi] = w1v[(ks * 16 + wv * 4 + hi) * 64 + lane];
#pragma unroll
    for (int hi = 0; hi < 4; ++hi)
#pragma unroll
      for (int pi = 0; pi < 4; ++pi)
        acc[hi][pi] = __builtin_amdgcn_mfma_f32_16x16x32_f16(
            wf[hi], xf[pi][ks], acc[hi][pi], 0, 0, 0);
  }

  __syncthreads();   // drains vmcnt(0): staged feat resident

  // ---- main loop ks=2..9: ff from LDS, wf double-buffered from global ----
#define LOAD_W(WB, S)                                                         \
  _Pragma("unroll") for (int hi = 0; hi < 4; ++hi)                            \
      WB[hi] = w1v[((S) * 16 + wv * 4 + hi) * 64 + lane];
#define LOAD_F(FB, S)                                                         \
  _Pragma("unroll") for (int pi = 0; pi < 4; ++pi)                            \
      FB[pi] = *(const half8v*)&smem[(((S) - 2) * 4 + pi) * 512 + lane * 8];
#define MFMA16(WB, FB)                                                        \
  _Pragma("unroll") for (int hi = 0; hi < 4; ++hi)                            \
      _Pragma("unroll") for (int pi = 0; pi < 4; ++pi)                        \
      acc[hi][pi] = __builtin_amdgcn_mfma_f32_16x16x32_f16(                   \
          WB[hi], FB[pi], acc[hi][pi], 0, 0, 0);

  {
    half8v wfA[4], wfB[4], fA[4];
    LOAD_W(wfA, 2);
    LOAD_F(fA, 2); LOAD_W(wfB, 3); MFMA16(wfA, fA);
    LOAD_F(fA, 3); LOAD_W(wfA, 4); MFMA16(wfB, fA);
    LOAD_F(fA, 4); LOAD_W(wfB, 5); MFMA16(wfA, fA);
    LOAD_F(fA, 5); LOAD_W(wfA, 6); MFMA16(wfB, fA);
    LOAD_F(fA, 6); LOAD_W(wfB, 7); MFMA16(wfA, fA);
    LOAD_F(fA, 7); LOAD_W(wfA, 8); MFMA16(wfB, fA);
    LOAD_F(fA, 8); LOAD_W(wfB, 9); MFMA16(wfA, fA);
    LOAD_F(fA, 9);                 MFMA16(wfB, fA);
  }

  float4 bias1[4];
#pragma unroll
  for (int hi = 0; hi < 4; ++hi)
    bias1[hi] = *(const float4*)&b1[n0 + hi * 16 + lg * 4];

  __syncthreads();   // staged-feat reads done; safe to alias with hbuf

  // ---- bias + packed-f16 GELU -> hbuf[px][hid] (8B writes) ----
#pragma unroll
  for (int hi = 0; hi < 4; ++hi) {
#pragma unroll
    for (int pi = 0; pi < 4; ++pi) {
      uint2 pk;
      pk.x = fast_gelu_pk(acc[hi][pi][0] + bias1[hi][0],
                          acc[hi][pi][1] + bias1[hi][1]);
      pk.y = fast_gelu_pk(acc[hi][pi][2] + bias1[hi][2],
                          acc[hi][pi][3] + bias1[hi][3]);
      *(uint2*)&smem[hs(pi * 16 + lr, n0 + hi * 16 + lg * 4)] = pk;
    }
  }
  __syncthreads();

  // ---- GEMM2: D[px 64][out 64]; wave wv does pixel rows 16wv..16wv+15 ----
  const int m0 = wv * 16;
  f32x4 acc2[4];
#pragma unroll
  for (int ni = 0; ni < 4; ++ni) acc2[ni] = 0;

  const half8v* w2v = (const half8v*)w2s;
#pragma unroll 2
  for (int ks = 0; ks < 8; ++ks) {
    half8v a2 = *(const half8v*)&smem[hs(m0 + lr, ks * 32 + lg * 8)];
#pragma unroll
    for (int ni = 0; ni < 4; ++ni) {
      half8v bfr = w2v[(ks * 4 + ni) * 64 + lane];
      acc2[ni] = __builtin_amdgcn_mfma_f32_16x16x32_f16(a2, bfr, acc2[ni],
                                                        0, 0, 0);
    }
  }

  // ---- epilogue: out = x + delta + b2 (x from fp16 copy; column-major) ----
#pragma unroll
  for (int ni = 0; ni < 4; ++ni) {
    const int col  = ni * 16 + lr;
    const float bias = b2[col];
#pragma unroll
    for (int q = 0; q < 4; ++q) {
      const int row = m0 + lg * 4 + q;
      const int py = row >> 3, px = row & 7;
      const size_t idx =
          ((size_t)(batch * H_ + tileY + py) * W_ + (tileX + px)) * C_ + col;
      out[idx] = (float)xh[idx] + acc2[ni][q] + bias;
    }
  }
#undef LOAD_W
#undef LOAD_F
#undef MFMA16
}

// ---------------------------------------------------------------------------
// FALLBACK (ws too small): fused fp32-x kernel (round-5 structure).
// ---------------------------------------------------------------------------
template <bool BOUND>
__device__ __forceinline__ void conv_phase_f32(const float* __restrict__ xb,
                                               const _Float16* __restrict__ cwh,
                                               ushort_t* __restrict__ feat,
                                               int tid, int tileX, int tileY) {
  const int quad = tid & 15;
  const int p0   = tid >> 4;
#pragma unroll
  for (int dd = 0; dd < 4; ++dd) {
    const int dil = 1 << dd;
    half2v w01[9], w23[9];
#pragma unroll
    for (int t = 0; t < 9; ++t) {
      uint2 wr = *(const uint2*)&cwh[(dd * 9 + t) * C_ + quad * 4];
      w01[t] = bch(wr.x);
      w23[t] = bch(wr.y);
    }
#pragma unroll
    for (int i = 0; i < 4; ++i) {
      const int p  = i * 16 + p0;
      const int y0 = tileY + (p >> 3), x0 = tileX + (p & 7);
      half2v a01 = {0, 0}, a23 = {0, 0};
#pragma unroll
      for (int ky = 0; ky < 3; ++ky) {
        const int yy = y0 + (ky - 1) * dil;
        if (BOUND && (unsigned)yy >= (unsigned)H_) continue;
#pragma unroll
        for (int kx = 0; kx < 3; ++kx) {
          const int xx = x0 + (kx - 1) * dil;
          if (BOUND && (unsigned)xx >= (unsigned)W_) continue;
          const int t = ky * 3 + kx;
          const float4 xv = *(const float4*)&xb[(yy * W_ + xx) * C_ + quad * 4];
          half2v xl = {(_Float16)xv.x, (_Float16)xv.y};
          half2v xh2 = {(_Float16)xv.z, (_Float16)xv.w};
          a01 += xl * w01[t];
          a23 += xh2 * w23[t];
        }
      }
      uint2 pk;
      pk.x = __builtin_bit_cast(uint32_t, a01);
      pk.y = __builtin_bit_cast(uint32_t, a23);
      *(uint2*)&feat[hs(p, dd * 64 + quad * 4)] = pk;
    }
  }
}

__global__ __launch_bounds__(256, 4)
void nca_fused_fp32(const float* __restrict__ x,
                    const _Float16* __restrict__ cwh,
                    const float* __restrict__ b1,
                    const float* __restrict__ b2,
                    const _Float16* __restrict__ w1s,
                    const _Float16* __restrict__ w2s,
                    float* __restrict__ out) {
  __shared__ __align__(16) ushort_t smem[64 * 256];

  const int tid   = threadIdx.x;
  const int tileX = blockIdx.x * 8;
  const int tileY = blockIdx.y * 8;
  const int batch = blockIdx.z;
  const float* xb = x + (size_t)batch * (H_ * W_ * C_);

  const int lane = tid & 63;
  const int wv   = tid >> 6;
  const int lr   = lane & 15;
  const int lg   = lane >> 4;
  const int n0   = wv * 64;

  half8v xf[4][2];
#pragma unroll
  for (int pi = 0; pi < 4; ++pi) {
    const int p  = pi * 16 + lr;
    const int gp = (tileY + (p >> 3)) * W_ + tileX + (p & 7);
#pragma unroll
    for (int ks = 0; ks < 2; ++ks) {
      const float* bp = &xb[gp * C_ + ks * 32 + lg * 8];
      float4 u = *(const float4*)bp, v = *(const float4*)(bp + 4);
      half8v s = {(_Float16)u.x, (_Float16)u.y, (_Float16)u.z, (_Float16)u.w,
                  (_Float16)v.x, (_Float16)v.y, (_Float16)v.z, (_Float16)v.w};
      xf[pi][ks] = s;
    }
  }

  const bool interior = (tileX >= 8) && (tileX <= W_ - 16) &&
                        (tileY >= 8) && (tileY <= H_ - 16);
  if (interior)
    conv_phase_f32<false>(xb, cwh, smem, tid, tileX, tileY);
  else
    conv_phase_f32<true>(xb, cwh, smem, tid, tileX, tileY);
  __syncthreads();

  f32x4 acc[4][4];
#pragma unroll
  for (int hi = 0; hi < 4; ++hi)
#pragma unroll
    for (int pi = 0; pi < 4; ++pi) acc[hi][pi] = 0;

  const half8v* w1v = (const half8v*)w1s;
#pragma unroll
  for (int ks = 0; ks < 2; ++ks) {
    half8v wf[4];
#pragma unroll
    for (int hi = 0; hi < 4; ++hi)
      wf[hi] = w1v[(ks * 16 + wv * 4 + hi) * 64 + lane];
#pragma unroll
    for (int hi = 0; hi < 4; ++hi)
#pragma unroll
      for (int pi = 0; pi < 4; ++pi)
        acc[hi][pi] = __builtin_amdgcn_mfma_f32_16x16x32_f16(
            wf[hi], xf[pi][ks], acc[hi][pi], 0, 0, 0);
  }
  for (int ks = 2; ks < 10; ++ks) {
    half8v ff[4], wf[4];
#pragma unroll
    for (int pi = 0; pi < 4; ++pi)
      ff[pi] = *(const half8v*)&smem[hs(pi * 16 + lr, (ks - 2) * 32 + lg * 8)];
#pragma unroll
    for (int hi = 0; hi < 4; ++hi)
      wf[hi] = w1v[(ks * 16 + wv * 4 + hi) * 64 + lane];
#pragma unroll
    for (int hi = 0; hi < 4; ++hi)
#pragma unroll
      for (int pi = 0; pi < 4; ++pi)
        acc[hi][pi] = __builtin_amdgcn_mfma_f32_16x16x32_f16(
            wf[hi], ff[pi], acc[hi][pi], 0, 0, 0);
  }

  float4 bias1[4];
#pragma unroll
  for (int hi = 0; hi < 4; ++hi)
    bias1[hi] = *(const float4*)&b1[n0 + hi * 16 + lg * 4];

  __syncthreads();

#pragma unroll
  for (int hi = 0; hi < 4; ++hi) {
#pragma unroll
    for (int pi = 0; pi < 4; ++pi) {
      _Float16 g[4];
#pragma unroll
      for (int q = 0; q < 4; ++q)
        g[q] = (_Float16)fast_gelu(acc[hi][pi][q] + bias1[hi][q]);
      half2v g01 = {g[0], g[1]}, g23 = {g[2], g[3]};
      uint2 pk;
      pk.x = __builtin_bit_cast(uint32_t, g01);
      pk.y = __builtin_bit_cast(uint32_t, g23);
      *(uint2*)&smem[hs(pi * 16 + lr, n0 + hi * 16 + lg * 4)] = pk;
    }
  }
  __syncthreads();

  const int m0 = wv * 16;
  f32x4 acc2[4];
#pragma unroll
  for (int ni = 0; ni < 4; ++ni) acc2[ni] = 0;

  const half8v* w2v = (const half8v*)w2s;
  for (int ks = 0; ks < 8; ++ks) {
    half8v a2 = *(const half8v*)&smem[hs(m0 + lr, ks * 32 + lg * 8)];
#pragma unroll
    for (int ni = 0; ni < 4; ++ni) {
      half8v bfr = w2v[(ks * 4 + ni) * 64 + lane];
      acc2[ni] = __builtin_amdgcn_mfma_f32_16x16x32_f16(a2, bfr, acc2[ni],
                                                        0, 0, 0);
    }
  }

#pragma unroll
  for (int ni = 0; ni < 4; ++ni) {
    const int col  = ni * 16 + lr;
    const float bias = b2[col];
#pragma unroll
    for (int q = 0; q < 4; ++q) {
      const int row = m0 + lg * 4 + q;
      const int py = row >> 3, px = row & 7;
      const size_t idx =
          ((size_t)(batch * H_ + tileY + py) * W_ + (tileX + px)) * C_ + col;
      out[idx] = x[idx] + acc2[ni][q] + bias;
    }
  }
}

extern "C" void kernel_launch(void* const* d_in, const int* in_sizes, int n_in,
                              void* d_out, int out_size, void* d_ws,
                              size_t ws_size, hipStream_t stream) {
  const float* x  = (const float*)d_in[0];
  const float* cw = (const float*)d_in[1];
  const float* W1 = (const float*)d_in[2];
  const float* b1 = (const float*)d_in[3];
  const float* W2 = (const float*)d_in[4];
  const float* b2 = (const float*)d_in[5];
  float* out = (float*)d_out;

  _Float16* wsb  = (_Float16*)d_ws;
  _Float16* w1s  = wsb + W1S_OFF;
  _Float16* w2s  = wsb + W2S_OFF;
  _Float16* cwh  = wsb + CWH_OFF;
  _Float16* xh   = wsb + XH_OFF;
  _Float16* feat = wsb + FEAT_OFF;

  if (ws_size >= (size_t)WS_NEED_FULL) {
    prep_kernel<<<393 + XELEMS / 8 / 256, 256, 0, stream>>>(x, W1, W2, cw, wsb);
    dim3 cgrid(W_ / 8, H_ / 8, B_ * 4);       // one dilation per block
    conv_all_kernel<<<cgrid, 256, 0, stream>>>(xh, cwh, feat);
    dim3 mgrid(W_ / 8, H_ / 8, B_);
    mlp_kernel<<<mgrid, 256, 0, stream>>>(xh, feat, b1, b2, w1s, w2s, out);
  } else {
    prep_kernel<<<393, 256, 0, stream>>>(x, W1, W2, cw, wsb);   // weights only
    dim3 grid(W_ / 8, H_ / 8, B_);
    nca_fused_fp32<<<grid, 256, 0, stream>>>(x, cwh, b1, b2, w1s, w2s, out);
  }
}

// Round 20
// 177.554 us; speedup vs baseline: 1.0940x; 1.0216x over previous
//
#include <hip/hip_runtime.h>
#include <hip/hip_fp16.h>
#include <cstdint>

#define B_   16
#define H_   128
#define W_   128
#define C_   64
#define HID_ 256
#define XELEMS (B_ * H_ * W_ * C_)   // 16777216

typedef _Float16 __attribute__((ext_vector_type(2))) half2v;
typedef _Float16 __attribute__((ext_vector_type(8))) half8v;   // MFMA frag, 4 VGPRs
typedef __attribute__((ext_vector_type(4))) float f32x4;
typedef unsigned short ushort_t;

// ws layout (in _Float16 elements)
#define W1S_OFF 0
#define W2S_OFF 81920
#define CWH_OFF 98304
#define XH_OFF  100608
#define FEAT_OFF (XH_OFF + XELEMS)                  // 16877824
#define FEAT_HALVES (4096ull * 16384ull)            // [tile][ks8][px64][c32]
#define WS_NEED_FULL (2ull * (FEAT_OFF + FEAT_HALVES))   // ~168 MB

// Bijective XOR-swizzled LDS index, row stride 256 halves (512 B).
__device__ __forceinline__ int hs(int row, int col) {
  return row * 256 + (((col >> 3) ^ (row & 7)) << 3) + (col & 7);
}

// scalar fast tanh-GELU (fallback path)
__device__ __forceinline__ float fast_gelu(float h) {
  float u = h * fmaf(h * h, 0.10293921f, 2.30211813f);
  float e = exp2f(-u);
  return h * __builtin_amdgcn_rcpf(1.0f + e);
}

// packed-f16 GELU (proven: mlp VALUBusy 38.6 -> ~24).
__device__ __forceinline__ uint32_t fast_gelu_pk(float h0, float h1) {
  half2v h = __builtin_bit_cast(half2v, __builtin_amdgcn_cvt_pkrtz(h0, h1));
  const half2v c1 = {(_Float16)0.10293921f, (_Float16)0.10293921f};
  const half2v c0 = {(_Float16)2.30211813f, (_Float16)2.30211813f};
  half2v u = h * (c0 + h * h * c1);
  __half2 e = h2exp2(__hneg2(__builtin_bit_cast(__half2, u)));
  const __half2 one = __half2{(__half)1.0f, (__half)1.0f};
  __half2 s = h2rcp(__hadd2(one, e));
  __half2 g = __hmul2(__builtin_bit_cast(__half2, h), s);
  return __builtin_bit_cast(uint32_t, g);
}

// async global->LDS, 16B per lane: LDS dest = wave-uniform base + lane*16.
__device__ __forceinline__ void stage16(const _Float16* g, const ushort_t* l) {
  __builtin_amdgcn_global_load_lds(
      (const __attribute__((address_space(1))) void*)g,
      (__attribute__((address_space(3))) void*)l, 16, 0, 0);
}

__device__ __forceinline__ half2v bch(uint32_t u) {
  return __builtin_bit_cast(half2v, u);
}

// ---------------------------------------------------------------------------
// prep: blocks [0,393): W1/W2 -> fp16 MFMA fragments + conv_w -> fp16.
//       blocks [393,...): x fp32 -> fp16 copy.
// ---------------------------------------------------------------------------
__global__ void prep_kernel(const float* __restrict__ x,
                            const float* __restrict__ W1,
                            const float* __restrict__ W2,
                            const float* __restrict__ cw,
                            _Float16* __restrict__ wsb) {
  if (blockIdx.x < 393) {
    int t = blockIdx.x * 256 + threadIdx.x;
    if (t < 81920) {
      int j = t & 7, lane = (t >> 3) & 63, n16 = (t >> 9) & 15, ks = t >> 13;
      int k = ks * 32 + (lane >> 4) * 8 + j;
      int n = n16 * 16 + (lane & 15);
      wsb[W1S_OFF + t] = (_Float16)W1[k * 256 + n];
    } else if (t < 98304) {
      int t2 = t - 81920;
      int j = t2 & 7, lane = (t2 >> 3) & 63, n16 = (t2 >> 9) & 3, ks = t2 >> 11;
      int k = ks * 32 + (lane >> 4) * 8 + j;
      int n = n16 * 16 + (lane & 15);
      wsb[W2S_OFF + t2] = (_Float16)W2[k * 64 + n];
    } else if (t < 98304 + 2304) {
      int t3 = t - 98304;
      wsb[CWH_OFF + t3] = (_Float16)cw[t3];   // [(dd*9+ky*3+kx)*64 + ch]
    }
  } else {
    int i = ((blockIdx.x - 393) * 256 + threadIdx.x) * 8;
    const float4 a = *(const float4*)&x[i];
    const float4 b = *(const float4*)&x[i + 4];
    half8v o = {(_Float16)a.x, (_Float16)a.y, (_Float16)a.z, (_Float16)a.w,
                (_Float16)b.x, (_Float16)b.y, (_Float16)b.z, (_Float16)b.w};
    *(half8v*)&wsb[XH_OFF + i] = o;
  }
}

// ---------------------------------------------------------------------------
// Boundary (register, predicated) conv path — rare tiles, runtime dil.
// ---------------------------------------------------------------------------
__device__ void conv_boundary(const _Float16* __restrict__ xhb,
                              const _Float16* __restrict__ cwh,
                              _Float16* __restrict__ ft,
                              int tid, int tileX, int tileY, int dil, int dd) {
  const int quad = tid & 15;
  const int p0   = tid >> 4;
  const int ksq  = quad >> 3;
  const int c32  = (quad & 7) * 4;

  half2v w01[9], w23[9];
#pragma unroll
  for (int t = 0; t < 9; ++t) {
    uint2 wr = *(const uint2*)&cwh[(dd * 9 + t) * C_ + quad * 4];
    w01[t] = bch(wr.x);
    w23[t] = bch(wr.y);
  }
#pragma unroll
  for (int i = 0; i < 4; ++i) {
    const int p  = i * 16 + p0;
    const int y0 = tileY + (p >> 3), x0 = tileX + (p & 7);
    half2v a01 = {0, 0}, a23 = {0, 0};
#pragma unroll
    for (int ky = 0; ky < 3; ++ky) {
      const int yy = y0 + (ky - 1) * dil;
#pragma unroll
      for (int kx = 0; kx < 3; ++kx) {
        const int xx = x0 + (kx - 1) * dil;
        uint2 vv = {0u, 0u};
        if ((unsigned)yy < (unsigned)H_ && (unsigned)xx < (unsigned)W_)
          vv = *(const uint2*)&xhb[(yy * W_ + xx) * C_ + quad * 4];
        const int t = ky * 3 + kx;
        a01 += bch(vv.x) * w01[t];
        a23 += bch(vv.y) * w23[t];
      }
    }
    uint2 pk;
    pk.x = __builtin_bit_cast(uint32_t, a01);
    pk.y = __builtin_bit_cast(uint32_t, a23);
    *(uint2*)&ft[(dd * 2 + ksq) * 2048 + p * 32 + c32] = pk;
  }
}

// ---------------------------------------------------------------------------
// conv_all (round-19 version): grid z = batch*4 + dd, launch_bounds (256,4).
//  dd<3 interior: stage (8+2*dil)x16-px region to LDS, taps via ds_read_b64.
//  dd==3: register path, 18x uint4 loads + asm liveness pin.
// ---------------------------------------------------------------------------
__global__ __launch_bounds__(256, 4)
void conv_all_kernel(const _Float16* __restrict__ xh,
                     const _Float16* __restrict__ cwh,
                     _Float16* __restrict__ feat) {
  __shared__ __align__(16) ushort_t lds[16 * 1024];   // 32 KB (R<=16 rows)

  const int tid   = threadIdx.x;
  const int tileX = blockIdx.x * 8;
  const int tileY = blockIdx.y * 8;
  const int batch = blockIdx.z >> 2;
  const int dd    = blockIdx.z & 3;
  const int dil   = 1 << dd;

  const _Float16* xhb = xh + (size_t)batch * (H_ * W_ * C_);
  _Float16* ft =
      feat + ((size_t)((batch * 16 + blockIdx.y) * 16 + blockIdx.x)) * 16384;

  const bool interior = (tileX >= 8) && (tileX <= W_ - 16) &&
                        (tileY >= 8) && (tileY <= H_ - 16);

  if (dd == 3) {
    const int c8 = tid & 7;
    const int p0 = tid >> 3;
    const int ksq = c8 >> 2;
    const int cof = (c8 & 3) * 8;

    uint4 wv4[9];
#pragma unroll
    for (int t = 0; t < 9; ++t)
      wv4[t] = *(const uint4*)&cwh[(3 * 9 + t) * C_ + c8 * 8];

    uint4 v[2][9];
#pragma unroll
    for (int i = 0; i < 2; ++i) {
      const int p  = i * 32 + p0;
      const int y0 = tileY + (p >> 3), x0 = tileX + (p & 7);
      if (interior) {
#pragma unroll
        for (int ky = 0; ky < 3; ++ky)
#pragma unroll
          for (int kx = 0; kx < 3; ++kx)
            v[i][ky * 3 + kx] = *(const uint4*)
                &xhb[((y0 + (ky - 1) * 8) * W_ + x0 + (kx - 1) * 8) * C_ +
                     c8 * 8];
      } else {
#pragma unroll
        for (int ky = 0; ky < 3; ++ky)
#pragma unroll
          for (int kx = 0; kx < 3; ++kx) {
            const int yy = y0 + (ky - 1) * 8;
            const int xx = x0 + (kx - 1) * 8;
            uint4 vv = {0u, 0u, 0u, 0u};
            if ((unsigned)yy < (unsigned)H_ && (unsigned)xx < (unsigned)W_)
              vv = *(const uint4*)&xhb[(yy * W_ + xx) * C_ + c8 * 8];
            v[i][ky * 3 + kx] = vv;
          }
      }
    }
#pragma unroll
    for (int i = 0; i < 2; ++i)
#pragma unroll
      for (int t = 0; t < 9; ++t)
        asm volatile("" : "+v"(v[i][t].x), "+v"(v[i][t].y),
                          "+v"(v[i][t].z), "+v"(v[i][t].w));

#pragma unroll
    for (int i = 0; i < 2; ++i) {
      const int p = i * 32 + p0;
      half2v a0 = {0, 0}, a1 = {0, 0}, a2 = {0, 0}, a3 = {0, 0};
#pragma unroll
      for (int t = 0; t < 9; ++t) {
        a0 += bch(v[i][t].x) * bch(wv4[t].x);
        a1 += bch(v[i][t].y) * bch(wv4[t].y);
        a2 += bch(v[i][t].z) * bch(wv4[t].z);
        a3 += bch(v[i][t].w) * bch(wv4[t].w);
      }
      uint4 pk;
      pk.x = __builtin_bit_cast(uint32_t, a0);
      pk.y = __builtin_bit_cast(uint32_t, a1);
      pk.z = __builtin_bit_cast(uint32_t, a2);
      pk.w = __builtin_bit_cast(uint32_t, a3);
      *(uint4*)&ft[(3 * 2 + ksq) * 2048 + p * 32 + cof] = pk;
    }
    return;
  }

  if (!interior) {
    conv_boundary(xhb, cwh, ft, tid, tileX, tileY, dil, dd);
    return;
  }

  const int lane = tid & 63;
  const int wv   = tid >> 6;
  const int quad = tid & 15;
  const int p0   = tid >> 4;
  const int ksq  = quad >> 3;
  const int c32  = (quad & 7) * 4;
  const int R    = 8 + 2 * dil;

  {
    const int x0 = tileX - dil, y0 = tileY - dil;
    for (int s = wv; s < 2 * R; s += 4) {
      const int row = s >> 1, half = s & 1;
      const _Float16* g =
          &xhb[((y0 + row) * W_ + x0 + half * 8 + (lane >> 3)) * C_ +
               (lane & 7) * 8];
      stage16(g, &lds[row * 1024 + half * 512]);
    }
  }

  half2v w01[9], w23[9];
#pragma unroll
  for (int t = 0; t < 9; ++t) {
    uint2 wr = *(const uint2*)&cwh[(dd * 9 + t) * C_ + quad * 4];
    w01[t] = bch(wr.x);
    w23[t] = bch(wr.y);
  }

  __syncthreads();   // drains vmcnt(0): region resident

#pragma unroll
  for (int i = 0; i < 4; ++i) {
    const int p  = i * 16 + p0;
    const int py = p >> 3, px = p & 7;
    uint2 tv[9];
#pragma unroll
    for (int ky = 0; ky < 3; ++ky)
#pragma unroll
      for (int kx = 0; kx < 3; ++kx)
        tv[ky * 3 + kx] = *(const uint2*)
            &lds[(py + ky * dil) * 1024 + (px + kx * dil) * 64 + quad * 4];
    half2v a01 = {0, 0}, a23 = {0, 0};
#pragma unroll
    for (int t = 0; t < 9; ++t) {
      a01 += bch(tv[t].x) * w01[t];
      a23 += bch(tv[t].y) * w23[t];
    }
    uint2 pk;
    pk.x = __builtin_bit_cast(uint32_t, a01);
    pk.y = __builtin_bit_cast(uint32_t, a23);
    *(uint2*)&ft[(dd * 2 + ksq) * 2048 + p * 32 + c32] = pk;
  }
}

// ---------------------------------------------------------------------------
// mlp v9: 512 threads = 8 waves per 8x8 tile; HALF-SIZE per-wave tile
// (acc[2][4] = 32 VGPR) to lift the occupancy cap (was 16 waves/CU from
// acc[4][4]=64). ALL GEMM1 A-operands (x ks0-1 + feat ks2-9) staged to LDS
// via global_load_lds (40 regions x 1KB = 40KB; zero VGPR landing cost).
// GEMM1: wave w owns hid rows w*32..w*32+31. GELU -> hbuf (aliases staged
// regions, barrier-protected). GEMM2: wave w = (px-quarter w&3, out-half
// w>>2), acc2[2]. Column-major scalar epilogue (proven store pattern).
// ---------------------------------------------------------------------------
__global__ __launch_bounds__(512, 5)
void mlp_kernel(const _Float16* __restrict__ xh,
                const _Float16* __restrict__ feat,
                const float* __restrict__ b1,
                const float* __restrict__ b2,
                const _Float16* __restrict__ w1s,
                const _Float16* __restrict__ w2s,
                float* __restrict__ out) {
  __shared__ __align__(16) ushort_t smem[40 * 512];   // 40 regions = 40 KB

  const int tid   = threadIdx.x;
  const int tileX = blockIdx.x * 8;
  const int tileY = blockIdx.y * 8;
  const int batch = blockIdx.z;
  const _Float16* xhb = xh + (size_t)batch * (H_ * W_ * C_);
  const _Float16* ftb =
      feat + ((size_t)((batch * 16 + blockIdx.y) * 16 + blockIdx.x)) * 16384;

  const int lane = tid & 63;
  const int w8   = tid >> 6;       // wave 0..7
  const int lr   = lane & 15;
  const int lg   = lane >> 4;
  const int n0   = w8 * 32;        // this wave's hid rows (GEMM1)

  const half8v* w1v = (const half8v*)w1s;

  // ---- stage ALL 40 A-operand regions (5 per wave) ----
  for (int r = w8; r < 40; r += 8) {
    const int ks = r >> 2, pi = r & 3;
    const int p  = pi * 16 + lr;
    const _Float16* g;
    if (ks < 2) {
      const int gp = (tileY + (p >> 3)) * W_ + tileX + (p & 7);
      g = &xhb[gp * C_ + ks * 32 + lg * 8];
    } else {
      g = &ftb[(ks - 2) * 2048 + p * 32 + lg * 8];
    }
    stage16(g, &smem[r * 512]);
  }

  // bias prefetch while stages are in flight
  float4 bias1[2];
#pragma unroll
  for (int hi = 0; hi < 2; ++hi)
    bias1[hi] = *(const float4*)&b1[n0 + hi * 16 + lg * 4];

  f32x4 acc[2][4];   // [hi][pi]
#pragma unroll
  for (int hi = 0; hi < 2; ++hi)
#pragma unroll
    for (int pi = 0; pi < 4; ++pi) acc[hi][pi] = 0;

  __syncthreads();   // drains vmcnt(0): all staged operands resident

  // ---- GEMM1 main loop ks=0..9: ff from LDS, wf double-buffered ----
#define LOAD_W(WB, S)                                                         \
  _Pragma("unroll") for (int hi = 0; hi < 2; ++hi)                            \
      WB[hi] = w1v[((S) * 16 + w8 * 2 + hi) * 64 + lane];
#define LOAD_F(FB, S)                                                         \
  _Pragma("unroll") for (int pi = 0; pi < 4; ++pi)                            \
      FB[pi] = *(const half8v*)&smem[((S) * 4 + pi) * 512 + lane * 8];
#define MFMA8(WB, FB)                                                         \
  _Pragma("unroll") for (int hi = 0; hi < 2; ++hi)                            \
      _Pragma("unroll") for (int pi = 0; pi < 4; ++pi)                        \
      acc[hi][pi] = __builtin_amdgcn_mfma_f32_16x16x32_f16(                   \
          WB[hi], FB[pi], acc[hi][pi], 0, 0, 0);

  {
    half8v wfA[2], wfB[2], fA[4];
    LOAD_W(wfA, 0);
    LOAD_F(fA, 0); LOAD_W(wfB, 1); MFMA8(wfA, fA);
    LOAD_F(fA, 1); LOAD_W(wfA, 2); MFMA8(wfB, fA);
    LOAD_F(fA, 2); LOAD_W(wfB, 3); MFMA8(wfA, fA);
    LOAD_F(fA, 3); LOAD_W(wfA, 4); MFMA8(wfB, fA);
    LOAD_F(fA, 4); LOAD_W(wfB, 5); MFMA8(wfA, fA);
    LOAD_F(fA, 5); LOAD_W(wfA, 6); MFMA8(wfB, fA);
    LOAD_F(fA, 6); LOAD_W(wfB, 7); MFMA8(wfA, fA);
    LOAD_F(fA, 7); LOAD_W(wfA, 8); MFMA8(wfB, fA);
    LOAD_F(fA, 8); LOAD_W(wfB, 9); MFMA8(wfA, fA);
    LOAD_F(fA, 9);                 MFMA8(wfB, fA);
  }

  __syncthreads();   // staged-region reads done; safe to alias with hbuf

  // ---- bias + packed-f16 GELU -> hbuf[px][hid] (first 32KB of smem) ----
#pragma unroll
  for (int hi = 0; hi < 2; ++hi) {
#pragma unroll
    for (int pi = 0; pi < 4; ++pi) {
      uint2 pk;
      pk.x = fast_gelu_pk(acc[hi][pi][0] + bias1[hi][0],
                          acc[hi][pi][1] + bias1[hi][1]);
      pk.y = fast_gelu_pk(acc[hi][pi][2] + bias1[hi][2],
                          acc[hi][pi][3] + bias1[hi][3]);
      *(uint2*)&smem[hs(pi * 16 + lr, n0 + hi * 16 + lg * 4)] = pk;
    }
  }
  __syncthreads();

  // ---- GEMM2: wave w8 = (px rows (w8&3)*16.., out blocks (w8>>2)*2..) ----
  const int m0    = (w8 & 3) * 16;
  const int nbase = (w8 >> 2) * 2;
  f32x4 acc2[2];
#pragma unroll
  for (int oi = 0; oi < 2; ++oi) acc2[oi] = 0;

  const half8v* w2v = (const half8v*)w2s;
#pragma unroll 2
  for (int ks = 0; ks < 8; ++ks) {
    half8v a2 = *(const half8v*)&smem[hs(m0 + lr, ks * 32 + lg * 8)];
#pragma unroll
    for (int oi = 0; oi < 2; ++oi) {
      half8v bfr = w2v[(ks * 4 + nbase + oi) * 64 + lane];
      acc2[oi] = __builtin_amdgcn_mfma_f32_16x16x32_f16(a2, bfr, acc2[oi],
                                                        0, 0, 0);
    }
  }

  // ---- epilogue: out = x + delta + b2 (fp16 residual, column-major) ----
#pragma unroll
  for (int oi = 0; oi < 2; ++oi) {
    const int col  = (nbase + oi) * 16 + lr;
    const float bias = b2[col];
#pragma unroll
    for (int q = 0; q < 4; ++q) {
      const int row = m0 + lg * 4 + q;
      const int py = row >> 3, px = row & 7;
      const size_t idx =
          ((size_t)(batch * H_ + tileY + py) * W_ + (tileX + px)) * C_ + col;
      out[idx] = (float)xh[idx] + acc2[oi][q] + bias;
    }
  }
#undef LOAD_W
#undef LOAD_F
#undef MFMA8
}

// ---------------------------------------------------------------------------
// FALLBACK (ws too small): fused fp32-x kernel (round-5 structure).
// ---------------------------------------------------------------------------
template <bool BOUND>
__device__ __forceinline__ void conv_phase_f32(const float* __restrict__ xb,
                                               const _Float16* __restrict__ cwh,
                                               ushort_t* __restrict__ feat,
                                               int tid, int tileX, int tileY) {
  const int quad = tid & 15;
  const int p0   = tid >> 4;
#pragma unroll
  for (int dd = 0; dd < 4; ++dd) {
    const int dil = 1 << dd;
    half2v w01[9], w23[9];
#pragma unroll
    for (int t = 0; t < 9; ++t) {
      uint2 wr = *(const uint2*)&cwh[(dd * 9 + t) * C_ + quad * 4];
      w01[t] = bch(wr.x);
      w23[t] = bch(wr.y);
    }
#pragma unroll
    for (int i = 0; i < 4; ++i) {
      const int p  = i * 16 + p0;
      const int y0 = tileY + (p >> 3), x0 = tileX + (p & 7);
      half2v a01 = {0, 0}, a23 = {0, 0};
#pragma unroll
      for (int ky = 0; ky < 3; ++ky) {
        const int yy = y0 + (ky - 1) * dil;
        if (BOUND && (unsigned)yy >= (unsigned)H_) continue;
#pragma unroll
        for (int kx = 0; kx < 3; ++kx) {
          const int xx = x0 + (kx - 1) * dil;
          if (BOUND && (unsigned)xx >= (unsigned)W_) continue;
          const int t = ky * 3 + kx;
          const float4 xv = *(const float4*)&xb[(yy * W_ + xx) * C_ + quad * 4];
          half2v xl = {(_Float16)xv.x, (_Float16)xv.y};
          half2v xh2 = {(_Float16)xv.z, (_Float16)xv.w};
          a01 += xl * w01[t];
          a23 += xh2 * w23[t];
        }
      }
      uint2 pk;
      pk.x = __builtin_bit_cast(uint32_t, a01);
      pk.y = __builtin_bit_cast(uint32_t, a23);
      *(uint2*)&feat[hs(p, dd * 64 + quad * 4)] = pk;
    }
  }
}

__global__ __launch_bounds__(256, 4)
void nca_fused_fp32(const float* __restrict__ x,
                    const _Float16* __restrict__ cwh,
                    const float* __restrict__ b1,
                    const float* __restrict__ b2,
                    const _Float16* __restrict__ w1s,
                    const _Float16* __restrict__ w2s,
                    float* __restrict__ out) {
  __shared__ __align__(16) ushort_t smem[64 * 256];

  const int tid   = threadIdx.x;
  const int tileX = blockIdx.x * 8;
  const int tileY = blockIdx.y * 8;
  const int batch = blockIdx.z;
  const float* xb = x + (size_t)batch * (H_ * W_ * C_);

  const int lane = tid & 63;
  const int wv   = tid >> 6;
  const int lr   = lane & 15;
  const int lg   = lane >> 4;
  const int n0   = wv * 64;

  half8v xf[4][2];
#pragma unroll
  for (int pi = 0; pi < 4; ++pi) {
    const int p  = pi * 16 + lr;
    const int gp = (tileY + (p >> 3)) * W_ + tileX + (p & 7);
#pragma unroll
    for (int ks = 0; ks < 2; ++ks) {
      const float* bp = &xb[gp * C_ + ks * 32 + lg * 8];
      float4 u = *(const float4*)bp, v = *(const float4*)(bp + 4);
      half8v s = {(_Float16)u.x, (_Float16)u.y, (_Float16)u.z, (_Float16)u.w,
                  (_Float16)v.x, (_Float16)v.y, (_Float16)v.z, (_Float16)v.w};
      xf[pi][ks] = s;
    }
  }

  const bool interior = (tileX >= 8) && (tileX <= W_ - 16) &&
                        (tileY >= 8) && (tileY <= H_ - 16);
  if (interior)
    conv_phase_f32<false>(xb, cwh, smem, tid, tileX, tileY);
  else
    conv_phase_f32<true>(xb, cwh, smem, tid, tileX, tileY);
  __syncthreads();

  f32x4 acc[4][4];
#pragma unroll
  for (int hi = 0; hi < 4; ++hi)
#pragma unroll
    for (int pi = 0; pi < 4; ++pi) acc[hi][pi] = 0;

  const half8v* w1v = (const half8v*)w1s;
#pragma unroll
  for (int ks = 0; ks < 2; ++ks) {
    half8v wf[4];
#pragma unroll
    for (int hi = 0; hi < 4; ++hi)
      wf[hi] = w1v[(ks * 16 + wv * 4 + hi) * 64 + lane];
#pragma unroll
    for (int hi = 0; hi < 4; ++hi)
#pragma unroll
      for (int pi = 0; pi < 4; ++pi)
        acc[hi][pi] = __builtin_amdgcn_mfma_f32_16x16x32_f16(
            wf[hi], xf[pi][ks], acc[hi][pi], 0, 0, 0);
  }
  for (int ks = 2; ks < 10; ++ks) {
    half8v ff[4], wf[4];
#pragma unroll
    for (int pi = 0; pi < 4; ++pi)
      ff[pi] = *(const half8v*)&smem[hs(pi * 16 + lr, (ks - 2) * 32 + lg * 8)];
#pragma unroll
    for (int hi = 0; hi < 4; ++hi)
      wf[hi] = w1v[(ks * 16 + wv * 4 + hi) * 64 + lane];
#pragma unroll
    for (int hi = 0; hi < 4; ++hi)
#pragma unroll
      for (int pi = 0; pi < 4; ++pi)
        acc[hi][pi] = __builtin_amdgcn_mfma_f32_16x16x32_f16(
            wf[hi], ff[pi], acc[hi][pi], 0, 0, 0);
  }

  float4 bias1[4];
#pragma unroll
  for (int hi = 0; hi < 4; ++hi)
    bias1[hi] = *(const float4*)&b1[n0 + hi * 16 + lg * 4];

  __syncthreads();

#pragma unroll
  for (int hi = 0; hi < 4; ++hi) {
#pragma unroll
    for (int pi = 0; pi < 4; ++pi) {
      _Float16 g[4];
#pragma unroll
      for (int q = 0; q < 4; ++q)
        g[q] = (_Float16)fast_gelu(acc[hi][pi][q] + bias1[hi][q]);
      half2v g01 = {g[0], g[1]}, g23 = {g[2], g[3]};
      uint2 pk;
      pk.x = __builtin_bit_cast(uint32_t, g01);
      pk.y = __builtin_bit_cast(uint32_t, g23);
      *(uint2*)&smem[hs(pi * 16 + lr, n0 + hi * 16 + lg * 4)] = pk;
    }
  }
  __syncthreads();

  const int m0 = wv * 16;
  f32x4 acc2[4];
#pragma unroll
  for (int ni = 0; ni < 4; ++ni) acc2[ni] = 0;

  const half8v* w2v = (const half8v*)w2s;
  for (int ks = 0; ks < 8; ++ks) {
    half8v a2 = *(const half8v*)&smem[hs(m0 + lr, ks * 32 + lg * 8)];
#pragma unroll
    for (int ni = 0; ni < 4; ++ni) {
      half8v bfr = w2v[(ks * 4 + ni) * 64 + lane];
      acc2[ni] = __builtin_amdgcn_mfma_f32_16x16x32_f16(a2, bfr, acc2[ni],
                                                        0, 0, 0);
    }
  }

#pragma unroll
  for (int ni = 0; ni < 4; ++ni) {
    const int col  = ni * 16 + lr;
    const float bias = b2[col];
#pragma unroll
    for (int q = 0; q < 4; ++q) {
      const int row = m0 + lg * 4 + q;
      const int py = row >> 3, px = row & 7;
      const size_t idx =
          ((size_t)(batch * H_ + tileY + py) * W_ + (tileX + px)) * C_ + col;
      out[idx] = x[idx] + acc2[ni][q] + bias;
    }
  }
}

extern "C" void kernel_launch(void* const* d_in, const int* in_sizes, int n_in,
                              void* d_out, int out_size, void* d_ws,
                              size_t ws_size, hipStream_t stream) {
  const float* x  = (const float*)d_in[0];
  const float* cw = (const float*)d_in[1];
  const float* W1 = (const float*)d_in[2];
  const float* b1 = (const float*)d_in[3];
  const float* W2 = (const float*)d_in[4];
  const float* b2 = (const float*)d_in[5];
  float* out = (float*)d_out;

  _Float16* wsb  = (_Float16*)d_ws;
  _Float16* w1s  = wsb + W1S_OFF;
  _Float16* w2s  = wsb + W2S_OFF;
  _Float16* cwh  = wsb + CWH_OFF;
  _Float16* xh   = wsb + XH_OFF;
  _Float16* feat = wsb + FEAT_OFF;

  if (ws_size >= (size_t)WS_NEED_FULL) {
    prep_kernel<<<393 + XELEMS / 8 / 256, 256, 0, stream>>>(x, W1, W2, cw, wsb);
    dim3 cgrid(W_ / 8, H_ / 8, B_ * 4);       // one dilation per block
    conv_all_kernel<<<cgrid, 256, 0, stream>>>(xh, cwh, feat);
    dim3 mgrid(W_ / 8, H_ / 8, B_);
    mlp_kernel<<<mgrid, 512, 0, stream>>>(xh, feat, b1, b2, w1s, w2s, out);
  } else {
    prep_kernel<<<393, 256, 0, stream>>>(x, W1, W2, cw, wsb);   // weights only
    dim3 grid(W_ / 8, H_ / 8, B_);
    nca_fused_fp32<<<grid, 256, 0, stream>>>(x, cwh, b1, b2, w1s, w2s, out);
  }
}